// Round 1
// baseline (1165.403 us; speedup 1.0000x reference)
//
#include <hip/hip_runtime.h>
#include <math.h>

constexpr int Bsz = 4, Lseq = 1024, Dmodel = 512, NLAYERS = 2;
constexpr int DI = 1024, NST = 16, RNK = 32;
constexpr int BLQ = Bsz * Lseq; // 4096 rows

// ---------------- embedding gather ----------------
__global__ __launch_bounds__(256) void embed_kernel(const int* __restrict__ x,
    const float* __restrict__ emb, float* __restrict__ H) {
  int i = blockIdx.x * 256 + threadIdx.x;        // one float4 per thread
  int row = (i * 4) / Dmodel, col = (i * 4) % Dmodel;
  int tok = x[row];
  *reinterpret_cast<float4*>(&H[(size_t)row * Dmodel + col]) =
      *reinterpret_cast<const float4*>(&emb[(size_t)tok * Dmodel + col]);
}

// ---------------- generic NT GEMM: C[m,n] = sum_k A[m,k]*B[n,k] ----------------
// EPI: 0 = plain store, 1 = softplus(acc + bias[n])
template<int BM, int BN, int BK, int TM, int TN, int EPI>
__global__ __launch_bounds__(256) void gemm_nt(
    const float* __restrict__ A, int lda,
    const float* __restrict__ B, int ldb,
    float* __restrict__ C, int ldc,
    int klen, size_t cslice, const float* __restrict__ bias)
{
  constexpr int NTX = BN / TN;
  constexpr int NTY = BM / TM;
  static_assert(NTX * NTY == 256, "thread count");
  static_assert(TN == 4, "float4 stores");
  __shared__ float As[BK][BM + 4];   // k-major (transposed) for vector reads
  __shared__ float Bs[BK][BN + 4];
  const int bn0 = blockIdx.x * BN;
  const int bm0 = blockIdx.y * BM;
  const int kbeg = blockIdx.z * klen;
  const int tid = threadIdx.x;
  const int tx = tid % NTX, ty = tid / NTX;
  float acc[TM][TN] = {};
  for (int kt = kbeg; kt < kbeg + klen; kt += BK) {
#pragma unroll
    for (int i = 0; i < BM * BK / 1024; ++i) {
      int idx = (tid + i * 256) * 4;
      int m = idx / BK, k = idx % BK;
      float4 v = *reinterpret_cast<const float4*>(&A[(size_t)(bm0 + m) * lda + kt + k]);
      As[k + 0][m] = v.x; As[k + 1][m] = v.y; As[k + 2][m] = v.z; As[k + 3][m] = v.w;
    }
#pragma unroll
    for (int i = 0; i < BN * BK / 1024; ++i) {
      int idx = (tid + i * 256) * 4;
      int n = idx / BK, k = idx % BK;
      float4 v = *reinterpret_cast<const float4*>(&B[(size_t)(bn0 + n) * ldb + kt + k]);
      Bs[k + 0][n] = v.x; Bs[k + 1][n] = v.y; Bs[k + 2][n] = v.z; Bs[k + 3][n] = v.w;
    }
    __syncthreads();
#pragma unroll
    for (int k = 0; k < BK; ++k) {
      float a[TM], b[TN];
#pragma unroll
      for (int i = 0; i < TM; i += 4)
        *reinterpret_cast<float4*>(&a[i]) = *reinterpret_cast<const float4*>(&As[k][ty * TM + i]);
#pragma unroll
      for (int j = 0; j < TN; j += 4)
        *reinterpret_cast<float4*>(&b[j]) = *reinterpret_cast<const float4*>(&Bs[k][tx * TN + j]);
#pragma unroll
      for (int i = 0; i < TM; ++i)
#pragma unroll
        for (int j = 0; j < TN; ++j)
          acc[i][j] = fmaf(a[i], b[j], acc[i][j]);
    }
    __syncthreads();
  }
  float* Cw = C + (size_t)blockIdx.z * cslice;
#pragma unroll
  for (int i = 0; i < TM; ++i) {
    int m = bm0 + ty * TM + i;
    float vv[4];
#pragma unroll
    for (int j = 0; j < TN; ++j) {
      float v = acc[i][j];
      if (EPI == 1) {
        v += bias[bn0 + tx * TN + j];
        v = (v > 15.f) ? v : log1pf(__expf(v));
      }
      vv[j] = v;
    }
    *reinterpret_cast<float4*>(&Cw[(size_t)m * ldc + bn0 + tx * TN]) =
        *reinterpret_cast<float4*>(vv);
  }
}

// ---------------- reduce 8 split-K partial slices ----------------
__global__ __launch_bounds__(256) void reduce8_kernel(const float* __restrict__ P,
    float* __restrict__ O, int n, int slice) {
  int i = blockIdx.x * 256 + threadIdx.x;
  if (i >= n) return;
  float s = 0.f;
#pragma unroll
  for (int j = 0; j < 8; ++j) s += P[(size_t)j * slice + i];
  O[i] = s;
}

// ---------------- depthwise causal conv (dc=3) + silu ----------------
__global__ __launch_bounds__(256) void conv_silu_kernel(
    const float* __restrict__ XZ, const float* __restrict__ cw,
    const float* __restrict__ cb, float* __restrict__ XC)
{
  int idx = blockIdx.x * 256 + threadIdx.x;   // over BLQ*DI
  int d = idx % DI;
  int bl = idx / DI;
  int l = bl % Lseq;
  size_t base = (size_t)bl * (2 * DI) + d;    // xi = XZ[..., 0:DI]
  float acc = cb[d];
  float w0 = cw[d * 3], w1 = cw[d * 3 + 1], w2 = cw[d * 3 + 2];
  if (l >= 2) acc = fmaf(XZ[base - 2 * (size_t)(2 * DI)], w0, acc);
  if (l >= 1) acc = fmaf(XZ[base - (size_t)(2 * DI)], w1, acc);
  acc = fmaf(XZ[base], w2, acc);
  XC[idx] = acc / (1.f + __expf(-acc));       // silu
}

// ---------------- selective scan, fused epilogue (in-place into XC) -----------
// block: (d-group of 16) x b ; tid = dsub*16 + n
__global__ __launch_bounds__(256) void scan_kernel(
    float* XC,                       // in: silu(conv); out: y (aliased, in-place)
    const float* __restrict__ DT, const float* __restrict__ DBC,
    const float* __restrict__ XZ, const float* __restrict__ A_log,
    const float* __restrict__ Dp)
{
  const int b = blockIdx.y;
  const int d0 = blockIdx.x * 16;
  const int tid = threadIdx.x;
  const int ds = tid >> 4, nn = tid & 15;
  const int d = d0 + ds;
  const float Adn = -__expf(A_log[d * NST + nn]);
  float h = 0.f;
  __shared__ float dt_s[64][16], xc_s[64][16], Bm_s[64][16], Cm_s[64][16], y_s[64][16];
  const size_t bL = (size_t)b * Lseq;
  for (int t0 = 0; t0 < Lseq; t0 += 64) {
#pragma unroll
    for (int i = 0; i < 4; ++i) {
      int e = tid + i * 256;
      int tt = e >> 4, j = e & 15;
      size_t g = (bL + t0 + tt) * DI + d0 + j;
      dt_s[tt][j] = DT[g];
      xc_s[tt][j] = XC[g];
      size_t gd = (bL + t0 + tt) * 64;
      Bm_s[tt][j] = DBC[gd + 32 + j];
      Cm_s[tt][j] = DBC[gd + 48 + j];
    }
    __syncthreads();
    for (int tt = 0; tt < 64; ++tt) {
      float dtv = dt_s[tt][ds];
      float dA = __expf(dtv * Adn);
      float u = dtv * xc_s[tt][ds] * Bm_s[tt][nn];
      h = fmaf(dA, h, u);
      float p = h * Cm_s[tt][nn];
      p += __shfl_xor(p, 1);
      p += __shfl_xor(p, 2);
      p += __shfl_xor(p, 4);
      p += __shfl_xor(p, 8);
      if (nn == 0) y_s[tt][ds] = p;
    }
    __syncthreads();
#pragma unroll
    for (int i = 0; i < 4; ++i) {
      int e = tid + i * 256;
      int tt = e >> 4, j = e & 15;
      size_t g = (bL + t0 + tt) * DI + d0 + j;
      float z = XZ[(bL + t0 + tt) * (2 * DI) + DI + d0 + j];
      float sil = z / (1.f + __expf(-z));
      XC[g] = (y_s[tt][j] + xc_s[tt][j] * Dp[d0 + j]) * sil;
    }
    __syncthreads();
  }
}

// ---------------- rmsnorm over D=512 ----------------
__global__ __launch_bounds__(256) void rmsnorm_kernel(const float* __restrict__ X,
    const float* __restrict__ W, float* __restrict__ O) {
  const int D = Dmodel;
  int row = blockIdx.x, tid = threadIdx.x;
  const float* xp = X + (size_t)row * D;
  float v0 = xp[tid], v1 = xp[tid + 256];
  float ss = v0 * v0 + v1 * v1;
#pragma unroll
  for (int o = 32; o >= 1; o >>= 1) ss += __shfl_xor(ss, o);
  __shared__ float wsum[4];
  if ((tid & 63) == 0) wsum[tid >> 6] = ss;
  __syncthreads();
  float tot = wsum[0] + wsum[1] + wsum[2] + wsum[3];
  float sc = rsqrtf(tot * (1.f / D) + 1e-5f);
  O[(size_t)row * D + tid] = v0 * sc * W[tid];
  O[(size_t)row * D + tid + 256] = v1 * sc * W[tid + 256];
}

// ---------------- mean-pool over L (deterministic, no atomics) ----------------
__global__ __launch_bounds__(256) void pool_kernel(const float* __restrict__ H,
    float* __restrict__ pooled) {
  int b = blockIdx.x, dgrp = blockIdx.y;
  int tid = threadIdx.x;
  int d = dgrp * 128 + (tid & 127);
  int ph = tid >> 7;
  const float* base = H + (size_t)b * Lseq * Dmodel + d;
  float s = 0.f;
  for (int t = ph; t < Lseq; t += 2) s += base[(size_t)t * Dmodel];
  __shared__ float red[256];
  red[tid] = s; __syncthreads();
  if (ph == 0) pooled[b * Dmodel + d] = (red[tid] + red[tid + 128]) * (1.f / Lseq);
}

// ---------------- tanh + fc head ----------------
__global__ __launch_bounds__(512) void head_kernel(const float* __restrict__ pooled,
    const float* __restrict__ fcw, const float* __restrict__ fcb,
    float* __restrict__ out) {
  int tid = threadIdx.x; // 512
  __shared__ float red[512];
  for (int b = 0; b < Bsz; ++b) {
    float th = tanhf(pooled[b * Dmodel + tid]);
    for (int j = 0; j < 2; ++j) {
      red[tid] = th * fcw[j * Dmodel + tid];
      __syncthreads();
      for (int s = 256; s > 0; s >>= 1) {
        if (tid < s) red[tid] += red[tid + s];
        __syncthreads();
      }
      if (tid == 0) out[b * 2 + j] = red[0] + fcb[j];
      __syncthreads();
    }
  }
}

extern "C" void kernel_launch(void* const* d_in, const int* in_sizes, int n_in,
                              void* d_out, int out_size, void* d_ws, size_t ws_size,
                              hipStream_t stream) {
  const int*   x      = (const int*)d_in[0];
  const float* emb    = (const float*)d_in[1];
  const float* norm_w = (const float*)d_in[2];
  const float* in_w   = (const float*)d_in[3];
  const float* conv_w = (const float*)d_in[4];
  const float* conv_b = (const float*)d_in[5];
  const float* xp_w   = (const float*)d_in[6];
  const float* dtp_w  = (const float*)d_in[7];
  const float* dtp_b  = (const float*)d_in[8];
  const float* A_log  = (const float*)d_in[9];
  const float* Dp     = (const float*)d_in[10];
  const float* out_w  = (const float*)d_in[11];
  const float* fc_w   = (const float*)d_in[12];
  const float* fc_b   = (const float*)d_in[13];
  float* out = (float*)d_out;

  float* ws   = (float*)d_ws;
  float* XZ   = ws;                                  // BLQ*2*DI      (32 MB)
  float* XC   = XZ  + (size_t)BLQ * 2 * DI;          // BLQ*DI        (16 MB)
  float* DTb  = XC  + (size_t)BLQ * DI;              // BLQ*DI        (16 MB)
  float* DBC  = DTb + (size_t)BLQ * DI;              // BLQ*64        (1 MB)
  float* DBCP = DBC + (size_t)BLQ * 64;              // 8*BLQ*64      (8 MB)
  float* H    = DBCP + (size_t)8 * BLQ * 64;         // BLQ*Dmodel    (8 MB)
  float* H2   = H   + (size_t)BLQ * Dmodel;          // BLQ*Dmodel    (8 MB)
  float* POOL = H2  + (size_t)BLQ * Dmodel;          // Bsz*Dmodel

  embed_kernel<<<BLQ * Dmodel / 1024, 256, 0, stream>>>(x, emb, H);

  for (int l = 0; l < NLAYERS; ++l) {
    const float* inw = in_w  + (size_t)l * 2 * DI * Dmodel;
    const float* cw  = conv_w + (size_t)l * DI * 3;
    const float* cb  = conv_b + (size_t)l * DI;
    const float* xpw = xp_w  + (size_t)l * 64 * DI;
    const float* dtw = dtp_w + (size_t)l * DI * RNK;
    const float* dtb = dtp_b + (size_t)l * DI;
    const float* Al  = A_log + (size_t)l * DI * NST;
    const float* dpl = Dp    + (size_t)l * DI;
    const float* ow  = out_w + (size_t)l * Dmodel * DI;
    const float* nw  = norm_w + (size_t)l * Dmodel;

    // xz = h @ in_w^T : M=4096, N=2048, K=512
    gemm_nt<128, 64, 32, 8, 4, 0><<<dim3(2 * DI / 64, BLQ / 128, 1), 256, 0, stream>>>(
        H, Dmodel, inw, Dmodel, XZ, 2 * DI, Dmodel, 0, nullptr);

    // xc = silu(causal depthwise conv(xi))
    conv_silu_kernel<<<BLQ * DI / 256, 256, 0, stream>>>(XZ, cw, cb, XC);

    // dbc = xc @ xp_w^T : M=4096, N=64, K=1024 -- split-K into 8 partial slices
    gemm_nt<128, 64, 32, 8, 4, 0><<<dim3(1, BLQ / 128, 8), 256, 0, stream>>>(
        XC, DI, xpw, DI, DBCP, 64, DI / 8, (size_t)BLQ * 64, nullptr);
    reduce8_kernel<<<BLQ * 64 / 256, 256, 0, stream>>>(DBCP, DBC, BLQ * 64, BLQ * 64);

    // dt = softplus(dbc[:, :32] @ dtp_w^T + dtp_b) : M=4096, N=1024, K=32
    gemm_nt<128, 64, 32, 8, 4, 1><<<dim3(DI / 64, BLQ / 128, 1), 256, 0, stream>>>(
        DBC, 64, dtw, RNK, DTb, DI, RNK, 0, dtb);

    // selective scan + (y + xc*Dp)*silu(z), in-place into XC
    scan_kernel<<<dim3(DI / 16, Bsz), 256, 0, stream>>>(XC, DTb, DBC, XZ, Al, dpl);

    // h2 = y @ out_w^T : M=4096, N=512, K=1024
    gemm_nt<128, 64, 32, 8, 4, 0><<<dim3(Dmodel / 64, BLQ / 128, 1), 256, 0, stream>>>(
        XC, DI, ow, DI, H2, Dmodel, DI, 0, nullptr);

    // h = rmsnorm(h2)
    rmsnorm_kernel<<<BLQ, 256, 0, stream>>>(H2, nw, H);
  }

  pool_kernel<<<dim3(Bsz, Dmodel / 128), 256, 0, stream>>>(H, POOL);
  head_kernel<<<1, 512, 0, stream>>>(POOL, fc_w, fc_b, out);
}

// Round 2
// 773.557 us; speedup vs baseline: 1.5066x; 1.5066x over previous
//
#include <hip/hip_runtime.h>
#include <math.h>

constexpr int Bsz = 4, Lseq = 1024, Dmodel = 512, NLAYERS = 2;
constexpr int DI = 1024, NST = 16, RNK = 32;
constexpr int BLQ = Bsz * Lseq; // 4096 rows
constexpr int NCH = 32, CLEN = 32; // chunked scan: 32 chunks x 32 steps

// ---------------- embedding gather ----------------
__global__ __launch_bounds__(256) void embed_kernel(const int* __restrict__ x,
    const float* __restrict__ emb, float* __restrict__ H) {
  int i = blockIdx.x * 256 + threadIdx.x;        // one float4 per thread
  int row = (i * 4) / Dmodel, col = (i * 4) % Dmodel;
  int tok = x[row];
  *reinterpret_cast<float4*>(&H[(size_t)row * Dmodel + col]) =
      *reinterpret_cast<const float4*>(&emb[(size_t)tok * Dmodel + col]);
}

// ---------------- generic NT GEMM: C[m,n] = sum_k A[m,k]*B[n,k] ----------------
// EPI: 0 = plain store, 1 = softplus(acc + bias[n])
template<int BM, int BN, int BK, int TM, int TN, int EPI>
__global__ __launch_bounds__(256) void gemm_nt(
    const float* __restrict__ A, int lda,
    const float* __restrict__ B, int ldb,
    float* __restrict__ C, int ldc,
    int klen, size_t cslice, const float* __restrict__ bias)
{
  constexpr int NTX = BN / TN;
  constexpr int NTY = BM / TM;
  static_assert(NTX * NTY == 256, "thread count");
  static_assert(TN == 4, "float4 stores");
  __shared__ float As[BK][BM + 4];   // k-major (transposed) for vector reads
  __shared__ float Bs[BK][BN + 4];
  const int bn0 = blockIdx.x * BN;
  const int bm0 = blockIdx.y * BM;
  const int kbeg = blockIdx.z * klen;
  const int tid = threadIdx.x;
  const int tx = tid % NTX, ty = tid / NTX;
  float acc[TM][TN] = {};
  for (int kt = kbeg; kt < kbeg + klen; kt += BK) {
#pragma unroll
    for (int i = 0; i < BM * BK / 1024; ++i) {
      int idx = (tid + i * 256) * 4;
      int m = idx / BK, k = idx % BK;
      float4 v = *reinterpret_cast<const float4*>(&A[(size_t)(bm0 + m) * lda + kt + k]);
      As[k + 0][m] = v.x; As[k + 1][m] = v.y; As[k + 2][m] = v.z; As[k + 3][m] = v.w;
    }
#pragma unroll
    for (int i = 0; i < BN * BK / 1024; ++i) {
      int idx = (tid + i * 256) * 4;
      int n = idx / BK, k = idx % BK;
      float4 v = *reinterpret_cast<const float4*>(&B[(size_t)(bn0 + n) * ldb + kt + k]);
      Bs[k + 0][n] = v.x; Bs[k + 1][n] = v.y; Bs[k + 2][n] = v.z; Bs[k + 3][n] = v.w;
    }
    __syncthreads();
#pragma unroll
    for (int k = 0; k < BK; ++k) {
      float a[TM], b[TN];
#pragma unroll
      for (int i = 0; i < TM; i += 4)
        *reinterpret_cast<float4*>(&a[i]) = *reinterpret_cast<const float4*>(&As[k][ty * TM + i]);
#pragma unroll
      for (int j = 0; j < TN; j += 4)
        *reinterpret_cast<float4*>(&b[j]) = *reinterpret_cast<const float4*>(&Bs[k][tx * TN + j]);
#pragma unroll
      for (int i = 0; i < TM; ++i)
#pragma unroll
        for (int j = 0; j < TN; ++j)
          acc[i][j] = fmaf(a[i], b[j], acc[i][j]);
    }
    __syncthreads();
  }
  float* Cw = C + (size_t)blockIdx.z * cslice;
#pragma unroll
  for (int i = 0; i < TM; ++i) {
    int m = bm0 + ty * TM + i;
    float vv[4];
#pragma unroll
    for (int j = 0; j < TN; ++j) {
      float v = acc[i][j];
      if (EPI == 1) {
        v += bias[bn0 + tx * TN + j];
        v = (v > 15.f) ? v : log1pf(__expf(v));
      }
      vv[j] = v;
    }
    *reinterpret_cast<float4*>(&Cw[(size_t)m * ldc + bn0 + tx * TN]) =
        *reinterpret_cast<float4*>(vv);
  }
}

// ---------------- reduce 8 split-K partial slices ----------------
__global__ __launch_bounds__(256) void reduce8_kernel(const float* __restrict__ P,
    float* __restrict__ O, int n, int slice) {
  int i = blockIdx.x * 256 + threadIdx.x;
  if (i >= n) return;
  float s = 0.f;
#pragma unroll
  for (int j = 0; j < 8; ++j) s += P[(size_t)j * slice + i];
  O[i] = s;
}

// ---------------- depthwise causal conv (dc=3) + silu ----------------
__global__ __launch_bounds__(256) void conv_silu_kernel(
    const float* __restrict__ XZ, const float* __restrict__ cw,
    const float* __restrict__ cb, float* __restrict__ XC)
{
  int idx = blockIdx.x * 256 + threadIdx.x;   // over BLQ*DI
  int d = idx % DI;
  int bl = idx / DI;
  int l = bl % Lseq;
  size_t base = (size_t)bl * (2 * DI) + d;    // xi = XZ[..., 0:DI]
  float acc = cb[d];
  float w0 = cw[d * 3], w1 = cw[d * 3 + 1], w2 = cw[d * 3 + 2];
  if (l >= 2) acc = fmaf(XZ[base - 2 * (size_t)(2 * DI)], w0, acc);
  if (l >= 1) acc = fmaf(XZ[base - (size_t)(2 * DI)], w1, acc);
  acc = fmaf(XZ[base], w2, acc);
  XC[idx] = acc / (1.f + __expf(-acc));       // silu
}

// ---------------- A = -exp(A_log) precompute ----------------
__global__ __launch_bounds__(256) void an_prep_kernel(const float* __restrict__ Al,
    float* __restrict__ AN) {
  int i = blockIdx.x * 256 + threadIdx.x;
  AN[i] = -expf(Al[i]);
}

// ---------------- chunked scan phase 1: per-chunk local scan ----------------
// thread = one (b, chunk, d); holds all 16 states in registers.
// outputs: local y (h0=0) -> YP, inclusive dt-cumsum (in-place into DTS),
//          chunk-final state -> HEND[b][c][d][n]
__global__ __launch_bounds__(256) void scan_p1_kernel(
    float* __restrict__ DTS, const float* __restrict__ XC,
    const float* __restrict__ DBC, const float* __restrict__ AN,
    float* __restrict__ YP, float* __restrict__ HEND)
{
  const int d = blockIdx.x * 256 + threadIdx.x;
  const int c = blockIdx.y, b = blockIdx.z;
  const int t0 = b * Lseq + c * CLEN;
  __shared__ float BC[CLEN][32];   // [t][0:16]=B, [t][16:32]=C
#pragma unroll
  for (int i = 0; i < CLEN * 32 / 256; ++i) {
    int e = threadIdx.x + i * 256;
    BC[e >> 5][e & 31] = DBC[(size_t)(t0 + (e >> 5)) * 64 + 32 + (e & 31)];
  }
  float An[16];
#pragma unroll
  for (int j = 0; j < 4; ++j)
    *reinterpret_cast<float4*>(&An[j * 4]) =
        *reinterpret_cast<const float4*>(&AN[d * 16 + j * 4]);
  __syncthreads();
  float h[16] = {};
  float S = 0.f;
#pragma unroll 4
  for (int t = 0; t < CLEN; ++t) {
    size_t g = (size_t)(t0 + t) * DI + d;
    float dt = DTS[g], xc = XC[g];
    S += dt;
    DTS[g] = S;
    float dtxc = dt * xc;
    float Bv[16], Cv[16];
#pragma unroll
    for (int j = 0; j < 4; ++j) {
      *reinterpret_cast<float4*>(&Bv[j * 4]) =
          *reinterpret_cast<const float4*>(&BC[t][j * 4]);
      *reinterpret_cast<float4*>(&Cv[j * 4]) =
          *reinterpret_cast<const float4*>(&BC[t][16 + j * 4]);
    }
    float y = 0.f;
#pragma unroll
    for (int n = 0; n < 16; ++n) {
      float dA = __expf(An[n] * dt);
      h[n] = fmaf(dA, h[n], dtxc * Bv[n]);
      y = fmaf(h[n], Cv[n], y);
    }
    YP[g] = y;
  }
  size_t hb = ((size_t)(b * NCH + c) * DI + d) * 16;
#pragma unroll
  for (int j = 0; j < 4; ++j)
    *reinterpret_cast<float4*>(&HEND[hb + j * 4]) =
        *reinterpret_cast<float4*>(&h[j * 4]);
}

// ---------------- chunked scan phase 2: combine chunk states ----------------
// thread = one (b,d,n); serial over 32 chunks. HEND rewritten in-place to the
// INITIAL state for each chunk.
__global__ __launch_bounds__(256) void scan_p2_kernel(
    float* __restrict__ HEND, const float* __restrict__ DTS,
    const float* __restrict__ AN)
{
  int id = blockIdx.x * 256 + threadIdx.x;   // (b,d,n)
  int n = id & 15, d = (id >> 4) & (DI - 1), b = id >> 14;
  float An = AN[d * 16 + n];
  float hg = 0.f;
  for (int c = 0; c < NCH; ++c) {
    size_t hi = ((size_t)(b * NCH + c) * DI + d) * 16 + n;
    float hl = HEND[hi];
    float Dc = DTS[(size_t)(b * Lseq + c * CLEN + CLEN - 1) * DI + d];
    HEND[hi] = hg;
    hg = fmaf(__expf(An * Dc), hg, hl);
  }
}

// ---------------- chunked scan phase 3: correction + fused epilogue ----------
// y_t = y_local_t + C_t . (exp(A*S_t) * h_init);  out = (y + xc*Dp)*silu(z)
__global__ __launch_bounds__(256) void scan_p3_kernel(
    float* __restrict__ XC, const float* __restrict__ YP,
    const float* __restrict__ DTS, const float* __restrict__ HEND,
    const float* __restrict__ DBC, const float* __restrict__ XZ,
    const float* __restrict__ AN, const float* __restrict__ Dp)
{
  size_t idx = (size_t)blockIdx.x * 256 + threadIdx.x;  // over (b,t,d)
  int d = (int)(idx & (DI - 1));
  int bt = (int)(idx >> 10);
  int b = bt >> 10, t = bt & (Lseq - 1);
  int c = t / CLEN;
  float S = DTS[idx];
  float An[16], hin[16], Cv[16];
  size_t hb = ((size_t)(b * NCH + c) * DI + d) * 16;
#pragma unroll
  for (int j = 0; j < 4; ++j) {
    *reinterpret_cast<float4*>(&An[j * 4]) =
        *reinterpret_cast<const float4*>(&AN[d * 16 + j * 4]);
    *reinterpret_cast<float4*>(&hin[j * 4]) =
        *reinterpret_cast<const float4*>(&HEND[hb + j * 4]);
    *reinterpret_cast<float4*>(&Cv[j * 4]) =
        *reinterpret_cast<const float4*>(&DBC[(size_t)bt * 64 + 48 + j * 4]);
  }
  float corr = 0.f;
#pragma unroll
  for (int n = 0; n < 16; ++n)
    corr = fmaf(Cv[n] * hin[n], __expf(An[n] * S), corr);
  float y = YP[idx] + corr;
  float xc = XC[idx];
  float z = XZ[(size_t)bt * 2 * DI + DI + d];
  float sil = z / (1.f + __expf(-z));
  XC[idx] = (y + xc * Dp[d]) * sil;
}

// ---------------- rmsnorm over D=512 ----------------
__global__ __launch_bounds__(256) void rmsnorm_kernel(const float* __restrict__ X,
    const float* __restrict__ W, float* __restrict__ O) {
  const int D = Dmodel;
  int row = blockIdx.x, tid = threadIdx.x;
  const float* xp = X + (size_t)row * D;
  float v0 = xp[tid], v1 = xp[tid + 256];
  float ss = v0 * v0 + v1 * v1;
#pragma unroll
  for (int o = 32; o >= 1; o >>= 1) ss += __shfl_xor(ss, o);
  __shared__ float wsum[4];
  if ((tid & 63) == 0) wsum[tid >> 6] = ss;
  __syncthreads();
  float tot = wsum[0] + wsum[1] + wsum[2] + wsum[3];
  float sc = rsqrtf(tot * (1.f / D) + 1e-5f);
  O[(size_t)row * D + tid] = v0 * sc * W[tid];
  O[(size_t)row * D + tid + 256] = v1 * sc * W[tid + 256];
}

// ---------------- mean-pool over L (deterministic, no atomics) ----------------
__global__ __launch_bounds__(256) void pool_kernel(const float* __restrict__ H,
    float* __restrict__ pooled) {
  int b = blockIdx.x, dgrp = blockIdx.y;
  int tid = threadIdx.x;
  int d = dgrp * 128 + (tid & 127);
  int ph = tid >> 7;
  const float* base = H + (size_t)b * Lseq * Dmodel + d;
  float s = 0.f;
  for (int t = ph; t < Lseq; t += 2) s += base[(size_t)t * Dmodel];
  __shared__ float red[256];
  red[tid] = s; __syncthreads();
  if (ph == 0) pooled[b * Dmodel + d] = (red[tid] + red[tid + 128]) * (1.f / Lseq);
}

// ---------------- tanh + fc head ----------------
__global__ __launch_bounds__(512) void head_kernel(const float* __restrict__ pooled,
    const float* __restrict__ fcw, const float* __restrict__ fcb,
    float* __restrict__ out) {
  int tid = threadIdx.x; // 512
  __shared__ float red[512];
  for (int b = 0; b < Bsz; ++b) {
    float th = tanhf(pooled[b * Dmodel + tid]);
    for (int j = 0; j < 2; ++j) {
      red[tid] = th * fcw[j * Dmodel + tid];
      __syncthreads();
      for (int s = 256; s > 0; s >>= 1) {
        if (tid < s) red[tid] += red[tid + s];
        __syncthreads();
      }
      if (tid == 0) out[b * 2 + j] = red[0] + fcb[j];
      __syncthreads();
    }
  }
}

extern "C" void kernel_launch(void* const* d_in, const int* in_sizes, int n_in,
                              void* d_out, int out_size, void* d_ws, size_t ws_size,
                              hipStream_t stream) {
  const int*   x      = (const int*)d_in[0];
  const float* emb    = (const float*)d_in[1];
  const float* norm_w = (const float*)d_in[2];
  const float* in_w   = (const float*)d_in[3];
  const float* conv_w = (const float*)d_in[4];
  const float* conv_b = (const float*)d_in[5];
  const float* xp_w   = (const float*)d_in[6];
  const float* dtp_w  = (const float*)d_in[7];
  const float* dtp_b  = (const float*)d_in[8];
  const float* A_log  = (const float*)d_in[9];
  const float* Dp     = (const float*)d_in[10];
  const float* out_w  = (const float*)d_in[11];
  const float* fc_w   = (const float*)d_in[12];
  const float* fc_b   = (const float*)d_in[13];
  float* out = (float*)d_out;

  float* ws   = (float*)d_ws;
  float* XZ   = ws;                                  // BLQ*2*DI      (32 MB)
  float* XC   = XZ  + (size_t)BLQ * 2 * DI;          // BLQ*DI        (16 MB)
  float* DTb  = XC  + (size_t)BLQ * DI;              // BLQ*DI        (16 MB)
  float* DBC  = DTb + (size_t)BLQ * DI;              // BLQ*64        (1 MB)
  float* DBCP = DBC + (size_t)BLQ * 64;              // 8*BLQ*64      (8 MB)
  float* H    = DBCP + (size_t)8 * BLQ * 64;         // BLQ*Dmodel    (8 MB)
  float* H2   = H   + (size_t)BLQ * Dmodel;          // BLQ*Dmodel    (8 MB)
  float* POOL = H2  + (size_t)BLQ * Dmodel;          // Bsz*Dmodel
  float* AN   = POOL + Bsz * Dmodel;                 // DI*NST        (64 KB)

  // scan scratch aliases (regions dead during the scan):
  float* YP   = H;      // BLQ*DI floats == H+H2 exactly; dead until gemm_out/rmsnorm
  float* HEND = DBCP;   // Bsz*NCH*DI*NST floats == DBCP size exactly

  embed_kernel<<<BLQ * Dmodel / 1024, 256, 0, stream>>>(x, emb, H);

  for (int l = 0; l < NLAYERS; ++l) {
    const float* inw = in_w  + (size_t)l * 2 * DI * Dmodel;
    const float* cw  = conv_w + (size_t)l * DI * 3;
    const float* cb  = conv_b + (size_t)l * DI;
    const float* xpw = xp_w  + (size_t)l * 64 * DI;
    const float* dtw = dtp_w + (size_t)l * DI * RNK;
    const float* dtb = dtp_b + (size_t)l * DI;
    const float* Al  = A_log + (size_t)l * DI * NST;
    const float* dpl = Dp    + (size_t)l * DI;
    const float* ow  = out_w + (size_t)l * Dmodel * DI;
    const float* nw  = norm_w + (size_t)l * Dmodel;

    // xz = h @ in_w^T : M=4096, N=2048, K=512
    gemm_nt<128, 64, 32, 8, 4, 0><<<dim3(2 * DI / 64, BLQ / 128, 1), 256, 0, stream>>>(
        H, Dmodel, inw, Dmodel, XZ, 2 * DI, Dmodel, 0, nullptr);

    // xc = silu(causal depthwise conv(xi))
    conv_silu_kernel<<<BLQ * DI / 256, 256, 0, stream>>>(XZ, cw, cb, XC);

    // dbc = xc @ xp_w^T : M=4096, N=64, K=1024 -- split-K into 8 partial slices
    gemm_nt<128, 64, 32, 8, 4, 0><<<dim3(1, BLQ / 128, 8), 256, 0, stream>>>(
        XC, DI, xpw, DI, DBCP, 64, DI / 8, (size_t)BLQ * 64, nullptr);
    reduce8_kernel<<<BLQ * 64 / 256, 256, 0, stream>>>(DBCP, DBC, BLQ * 64, BLQ * 64);

    // dt = softplus(dbc[:, :32] @ dtp_w^T + dtp_b) : M=4096, N=1024, K=32
    gemm_nt<128, 64, 32, 8, 4, 1><<<dim3(DI / 64, BLQ / 128, 1), 256, 0, stream>>>(
        DBC, 64, dtw, RNK, DTb, DI, RNK, 0, dtb);

    // chunked selective scan (3 phases) + fused (y + xc*Dp)*silu(z) epilogue
    an_prep_kernel<<<DI * NST / 256, 256, 0, stream>>>(Al, AN);
    scan_p1_kernel<<<dim3(DI / 256, NCH, Bsz), 256, 0, stream>>>(
        DTb, XC, DBC, AN, YP, HEND);
    scan_p2_kernel<<<Bsz * DI * NST / 256, 256, 0, stream>>>(HEND, DTb, AN);
    scan_p3_kernel<<<BLQ * DI / 256, 256, 0, stream>>>(
        XC, YP, DTb, HEND, DBC, XZ, AN, dpl);

    // h2 = y @ out_w^T : M=4096, N=512, K=1024
    gemm_nt<128, 64, 32, 8, 4, 0><<<dim3(Dmodel / 64, BLQ / 128, 1), 256, 0, stream>>>(
        XC, DI, ow, DI, H2, Dmodel, DI, 0, nullptr);

    // h = rmsnorm(h2)
    rmsnorm_kernel<<<BLQ, 256, 0, stream>>>(H2, nw, H);
  }

  pool_kernel<<<dim3(Bsz, Dmodel / 128), 256, 0, stream>>>(H, POOL);
  head_kernel<<<1, 512, 0, stream>>>(POOL, fc_w, fc_b, out);
}

// Round 4
// 443.763 us; speedup vs baseline: 2.6262x; 1.7432x over previous
//
#include <hip/hip_runtime.h>
#include <math.h>

constexpr int Bsz = 4, Lseq = 1024, Dmodel = 512, NLAYERS = 2;
constexpr int DI = 1024, NST = 16, RNK = 32;
constexpr int BLQ = Bsz * Lseq; // 4096 rows
constexpr int NCH = 32, CLEN = 32; // chunked scan: 32 chunks x 32 steps

typedef __attribute__((ext_vector_type(8))) short short8v;   // 8 bf16
typedef __attribute__((ext_vector_type(8))) unsigned short ushort8v;
typedef __attribute__((ext_vector_type(4))) float f32x4;
typedef unsigned short ushort;

// ---------------- embedding gather ----------------
__global__ __launch_bounds__(256) void embed_kernel(const int* __restrict__ x,
    const float* __restrict__ emb, float* __restrict__ H) {
  int i = blockIdx.x * 256 + threadIdx.x;        // one float4 per thread
  int row = (i * 4) / Dmodel, col = (i * 4) % Dmodel;
  int tok = x[row];
  *reinterpret_cast<float4*>(&H[(size_t)row * Dmodel + col]) =
      *reinterpret_cast<const float4*>(&emb[(size_t)tok * Dmodel + col]);
}

// ---------------- fp32 -> split bf16 (hi/lo), fragment-tiled layout ----------
// dest chunk layout per (rowtile rt, ktile kt): [kk(2)][msub(8)][lane(64)][8]
// lane = (row&15) | (k8&3)<<4 ; k = kt*64 + kk*32 + (lane>>4)*8
template<int K>
__global__ __launch_bounds__(256) void cvt_frag_kernel(
    const float* __restrict__ X, ushort* __restrict__ Xh, ushort* __restrict__ Xl)
{
  constexpr int K8 = K / 8, KT = K / 64;
  int linear = blockIdx.x * 256 + threadIdx.x;
  int row = linear / K8;
  int k = (linear - row * K8) * 8;
  const float* src = X + (size_t)row * K + k;
  float4 v0 = *reinterpret_cast<const float4*>(src);
  float4 v1 = *reinterpret_cast<const float4*>(src + 4);
  float xs[8] = {v0.x, v0.y, v0.z, v0.w, v1.x, v1.y, v1.z, v1.w};
  ushort hs[8], ls[8];
#pragma unroll
  for (int j = 0; j < 8; ++j) {
    unsigned u = __float_as_uint(xs[j]);
    float hf = __uint_as_float(u & 0xFFFF0000u);
    float r = xs[j] - hf;                        // exact
    hs[j] = (ushort)(u >> 16);
    ls[j] = (ushort)(__float_as_uint(r) >> 16);
  }
  int kt = k >> 6, kk = (k >> 5) & 1, k8 = (k >> 3) & 3;
  int rt = row >> 7, msub = (row >> 4) & 7, lr = row & 15;
  int lanei = lr | (k8 << 4);
  size_t d = ((((size_t)(rt * KT + kt) * 2 + kk) * 8 + msub) * 64 + lanei) * 8;
  *reinterpret_cast<ushort8v*>(&Xh[d]) = *reinterpret_cast<ushort8v*>(hs);
  *reinterpret_cast<ushort8v*>(&Xl[d]) = *reinterpret_cast<ushort8v*>(ls);
}

// ---------------- split-bf16 MFMA GEMM: C[m,n] = sum_k A[m,k]B[n,k] ----------
// BM=BN=128, BK=64; 4 waves (2x2); 3 products (hh, hl, lh) per tile.
__global__ __launch_bounds__(256) void gemm_mfma(
    const ushort* __restrict__ Ah, const ushort* __restrict__ Al,
    const ushort* __restrict__ Bh, const ushort* __restrict__ Bl,
    float* __restrict__ C, int N, int K)
{
  const int KT = K >> 6;
  constexpr int ASZ = 2 * 8 * 64 * 8;   // 8192 ushorts = 16KB per array
  __shared__ ushort lds[4 * ASZ];       // Ah | Al | Bh | Bl

  const int tid = threadIdx.x;
  const int lane = tid & 63, wid = tid >> 6;
  const int wm = wid >> 1, wn = wid & 1;
  const int bm0 = blockIdx.y * 128, bn0 = blockIdx.x * 128;
  const size_t abase = (size_t)blockIdx.y * KT * ASZ;
  const size_t bbase = (size_t)blockIdx.x * KT * ASZ;

  // each wave stages one array (wave0:Ah, 1:Al, 2:Bh, 3:Bl)
  const ushort* gsrc = (wid == 0) ? Ah : (wid == 1) ? Al : (wid == 2) ? Bh : Bl;
  const size_t gb = (wid < 2) ? abase : bbase;

  f32x4 acc[4][4];
#pragma unroll
  for (int i = 0; i < 4; ++i)
#pragma unroll
    for (int j = 0; j < 4; ++j) acc[i][j] = (f32x4){0.f, 0.f, 0.f, 0.f};

  const int msel = wm * 4, nsel = wn * 4;

  for (int kt = 0; kt < KT; ++kt) {
    const ushort* sbase = gsrc + gb + (size_t)kt * ASZ + lane * 8;
#pragma unroll
    for (int i = 0; i < 16; ++i) {
      __builtin_amdgcn_global_load_lds(
          (const __attribute__((address_space(1))) void*)(sbase + i * 512),
          (__attribute__((address_space(3))) void*)(lds + wid * ASZ + i * 512),
          16, 0, 0);
    }
    __syncthreads();
#pragma unroll
    for (int kk = 0; kk < 2; ++kk) {
      short8v a_h[4], a_l[4], b_h[4], b_l[4];
#pragma unroll
      for (int i = 0; i < 4; ++i) {
        int ai = ((kk * 8 + msel + i) * 64 + lane) * 8;
        int bi = ((kk * 8 + nsel + i) * 64 + lane) * 8;
        a_h[i] = *reinterpret_cast<const short8v*>(&lds[0 * ASZ + ai]);
        a_l[i] = *reinterpret_cast<const short8v*>(&lds[1 * ASZ + ai]);
        b_h[i] = *reinterpret_cast<const short8v*>(&lds[2 * ASZ + bi]);
        b_l[i] = *reinterpret_cast<const short8v*>(&lds[3 * ASZ + bi]);
      }
#pragma unroll
      for (int ms = 0; ms < 4; ++ms)
#pragma unroll
        for (int ns = 0; ns < 4; ++ns) {
          acc[ms][ns] = __builtin_amdgcn_mfma_f32_16x16x32_bf16(a_h[ms], b_h[ns], acc[ms][ns], 0, 0, 0);
          acc[ms][ns] = __builtin_amdgcn_mfma_f32_16x16x32_bf16(a_h[ms], b_l[ns], acc[ms][ns], 0, 0, 0);
          acc[ms][ns] = __builtin_amdgcn_mfma_f32_16x16x32_bf16(a_l[ms], b_h[ns], acc[ms][ns], 0, 0, 0);
        }
    }
    __syncthreads();
  }

  const int cr = lane >> 4, cc = lane & 15;
#pragma unroll
  for (int ms = 0; ms < 4; ++ms) {
    int row0 = bm0 + (msel + ms) * 16 + cr * 4;
#pragma unroll
    for (int ns = 0; ns < 4; ++ns) {
      int col = bn0 + (nsel + ns) * 16 + cc;
#pragma unroll
      for (int r = 0; r < 4; ++r)
        C[(size_t)(row0 + r) * N + col] = acc[ms][ns][r];
    }
  }
}

// ---------------- generic NT GEMM (fp32 vector), small GEMMs ----------------
template<int BM, int BN, int BK, int TM, int TN, int EPI>
__global__ __launch_bounds__(256) void gemm_nt(
    const float* __restrict__ A, int lda,
    const float* __restrict__ B, int ldb,
    float* __restrict__ C, int ldc,
    int klen, size_t cslice, const float* __restrict__ bias)
{
  constexpr int NTX = BN / TN;
  constexpr int NTY = BM / TM;
  static_assert(NTX * NTY == 256, "thread count");
  static_assert(TN == 4, "float4 stores");
  __shared__ float As[BK][BM + 4];
  __shared__ float Bs[BK][BN + 4];
  const int bn0 = blockIdx.x * BN;
  const int bm0 = blockIdx.y * BM;
  const int kbeg = blockIdx.z * klen;
  const int tid = threadIdx.x;
  const int tx = tid % NTX, ty = tid / NTX;
  float acc[TM][TN] = {};
  for (int kt = kbeg; kt < kbeg + klen; kt += BK) {
#pragma unroll
    for (int i = 0; i < BM * BK / 1024; ++i) {
      int idx = (tid + i * 256) * 4;
      int m = idx / BK, k = idx % BK;
      float4 v = *reinterpret_cast<const float4*>(&A[(size_t)(bm0 + m) * lda + kt + k]);
      As[k + 0][m] = v.x; As[k + 1][m] = v.y; As[k + 2][m] = v.z; As[k + 3][m] = v.w;
    }
#pragma unroll
    for (int i = 0; i < BN * BK / 1024; ++i) {
      int idx = (tid + i * 256) * 4;
      int n = idx / BK, k = idx % BK;
      float4 v = *reinterpret_cast<const float4*>(&B[(size_t)(bn0 + n) * ldb + kt + k]);
      Bs[k + 0][n] = v.x; Bs[k + 1][n] = v.y; Bs[k + 2][n] = v.z; Bs[k + 3][n] = v.w;
    }
    __syncthreads();
#pragma unroll
    for (int k = 0; k < BK; ++k) {
      float a[TM], b[TN];
#pragma unroll
      for (int i = 0; i < TM; i += 4)
        *reinterpret_cast<float4*>(&a[i]) = *reinterpret_cast<const float4*>(&As[k][ty * TM + i]);
#pragma unroll
      for (int j = 0; j < TN; j += 4)
        *reinterpret_cast<float4*>(&b[j]) = *reinterpret_cast<const float4*>(&Bs[k][tx * TN + j]);
#pragma unroll
      for (int i = 0; i < TM; ++i)
#pragma unroll
        for (int j = 0; j < TN; ++j)
          acc[i][j] = fmaf(a[i], b[j], acc[i][j]);
    }
    __syncthreads();
  }
  float* Cw = C + (size_t)blockIdx.z * cslice;
#pragma unroll
  for (int i = 0; i < TM; ++i) {
    int m = bm0 + ty * TM + i;
    float vv[4];
#pragma unroll
    for (int j = 0; j < TN; ++j) {
      float v = acc[i][j];
      if (EPI == 1) {
        v += bias[bn0 + tx * TN + j];
        v = (v > 15.f) ? v : log1pf(__expf(v));
      }
      vv[j] = v;
    }
    *reinterpret_cast<float4*>(&Cw[(size_t)m * ldc + bn0 + tx * TN]) =
        *reinterpret_cast<float4*>(vv);
  }
}

// ---------------- reduce 8 split-K partial slices ----------------
__global__ __launch_bounds__(256) void reduce8_kernel(const float* __restrict__ P,
    float* __restrict__ O, int n, int slice) {
  int i = blockIdx.x * 256 + threadIdx.x;
  if (i >= n) return;
  float s = 0.f;
#pragma unroll
  for (int j = 0; j < 8; ++j) s += P[(size_t)j * slice + i];
  O[i] = s;
}

// ---------------- depthwise causal conv (dc=3) + silu ----------------
__global__ __launch_bounds__(256) void conv_silu_kernel(
    const float* __restrict__ XZ, const float* __restrict__ cw,
    const float* __restrict__ cb, float* __restrict__ XC)
{
  int idx = blockIdx.x * 256 + threadIdx.x;   // over BLQ*DI
  int d = idx % DI;
  int bl = idx / DI;
  int l = bl % Lseq;
  size_t base = (size_t)bl * (2 * DI) + d;    // xi = XZ[..., 0:DI]
  float acc = cb[d];
  float w0 = cw[d * 3], w1 = cw[d * 3 + 1], w2 = cw[d * 3 + 2];
  if (l >= 2) acc = fmaf(XZ[base - 2 * (size_t)(2 * DI)], w0, acc);
  if (l >= 1) acc = fmaf(XZ[base - (size_t)(2 * DI)], w1, acc);
  acc = fmaf(XZ[base], w2, acc);
  XC[idx] = acc / (1.f + __expf(-acc));       // silu
}

// ---------------- A = -exp(A_log) precompute ----------------
__global__ __launch_bounds__(256) void an_prep_kernel(const float* __restrict__ Al,
    float* __restrict__ AN) {
  int i = blockIdx.x * 256 + threadIdx.x;
  AN[i] = -expf(Al[i]);
}

// ---------------- chunked scan phase 1 ----------------
__global__ __launch_bounds__(256) void scan_p1_kernel(
    float* __restrict__ DTS, const float* __restrict__ XC,
    const float* __restrict__ DBC, const float* __restrict__ AN,
    float* __restrict__ YP, float* __restrict__ HEND)
{
  const int d = blockIdx.x * 256 + threadIdx.x;
  const int c = blockIdx.y, b = blockIdx.z;
  const int t0 = b * Lseq + c * CLEN;
  __shared__ float BC[CLEN][32];   // [t][0:16]=B, [t][16:32]=C
#pragma unroll
  for (int i = 0; i < CLEN * 32 / 256; ++i) {
    int e = threadIdx.x + i * 256;
    BC[e >> 5][e & 31] = DBC[(size_t)(t0 + (e >> 5)) * 64 + 32 + (e & 31)];
  }
  float An[16];
#pragma unroll
  for (int j = 0; j < 4; ++j)
    *reinterpret_cast<float4*>(&An[j * 4]) =
        *reinterpret_cast<const float4*>(&AN[d * 16 + j * 4]);
  __syncthreads();
  float h[16] = {};
  float S = 0.f;
#pragma unroll 4
  for (int t = 0; t < CLEN; ++t) {
    size_t g = (size_t)(t0 + t) * DI + d;
    float dt = DTS[g], xc = XC[g];
    S += dt;
    DTS[g] = S;
    float dtxc = dt * xc;
    float Bv[16], Cv[16];
#pragma unroll
    for (int j = 0; j < 4; ++j) {
      *reinterpret_cast<float4*>(&Bv[j * 4]) =
          *reinterpret_cast<const float4*>(&BC[t][j * 4]);
      *reinterpret_cast<float4*>(&Cv[j * 4]) =
          *reinterpret_cast<const float4*>(&BC[t][16 + j * 4]);
    }
    float y = 0.f;
#pragma unroll
    for (int n = 0; n < 16; ++n) {
      float dA = __expf(An[n] * dt);
      h[n] = fmaf(dA, h[n], dtxc * Bv[n]);
      y = fmaf(h[n], Cv[n], y);
    }
    YP[g] = y;
  }
  size_t hb = ((size_t)(b * NCH + c) * DI + d) * 16;
#pragma unroll
  for (int j = 0; j < 4; ++j)
    *reinterpret_cast<float4*>(&HEND[hb + j * 4]) =
        *reinterpret_cast<float4*>(&h[j * 4]);
}

// ---------------- chunked scan phase 2 ----------------
__global__ __launch_bounds__(256) void scan_p2_kernel(
    float* __restrict__ HEND, const float* __restrict__ DTS,
    const float* __restrict__ AN)
{
  int id = blockIdx.x * 256 + threadIdx.x;   // (b,d,n)
  int n = id & 15, d = (id >> 4) & (DI - 1), b = id >> 14;
  float An = AN[d * 16 + n];
  float hg = 0.f;
  for (int c = 0; c < NCH; ++c) {
    size_t hi = ((size_t)(b * NCH + c) * DI + d) * 16 + n;
    float hl = HEND[hi];
    float Dc = DTS[(size_t)(b * Lseq + c * CLEN + CLEN - 1) * DI + d];
    HEND[hi] = hg;
    hg = fmaf(__expf(An * Dc), hg, hl);
  }
}

// ---------------- chunked scan phase 3 + fused epilogue ----------------
__global__ __launch_bounds__(256) void scan_p3_kernel(
    float* __restrict__ XC, const float* __restrict__ YP,
    const float* __restrict__ DTS, const float* __restrict__ HEND,
    const float* __restrict__ DBC, const float* __restrict__ XZ,
    const float* __restrict__ AN, const float* __restrict__ Dp)
{
  size_t idx = (size_t)blockIdx.x * 256 + threadIdx.x;  // over (b,t,d)
  int d = (int)(idx & (DI - 1));
  int bt = (int)(idx >> 10);
  int b = bt >> 10, t = bt & (Lseq - 1);
  int c = t / CLEN;
  float S = DTS[idx];
  float An[16], hin[16], Cv[16];
  size_t hb = ((size_t)(b * NCH + c) * DI + d) * 16;
#pragma unroll
  for (int j = 0; j < 4; ++j) {
    *reinterpret_cast<float4*>(&An[j * 4]) =
        *reinterpret_cast<const float4*>(&AN[d * 16 + j * 4]);
    *reinterpret_cast<float4*>(&hin[j * 4]) =
        *reinterpret_cast<const float4*>(&HEND[hb + j * 4]);
    *reinterpret_cast<float4*>(&Cv[j * 4]) =
        *reinterpret_cast<const float4*>(&DBC[(size_t)bt * 64 + 48 + j * 4]);
  }
  float corr = 0.f;
#pragma unroll
  for (int n = 0; n < 16; ++n)
    corr = fmaf(Cv[n] * hin[n], __expf(An[n] * S), corr);
  float y = YP[idx] + corr;
  float xc = XC[idx];
  float z = XZ[(size_t)bt * 2 * DI + DI + d];
  float sil = z / (1.f + __expf(-z));
  XC[idx] = (y + xc * Dp[d]) * sil;
}

// ---------------- rmsnorm over D=512 ----------------
__global__ __launch_bounds__(256) void rmsnorm_kernel(const float* __restrict__ X,
    const float* __restrict__ W, float* __restrict__ O) {
  const int D = Dmodel;
  int row = blockIdx.x, tid = threadIdx.x;
  const float* xp = X + (size_t)row * D;
  float v0 = xp[tid], v1 = xp[tid + 256];
  float ss = v0 * v0 + v1 * v1;
#pragma unroll
  for (int o = 32; o >= 1; o >>= 1) ss += __shfl_xor(ss, o);
  __shared__ float wsum[4];
  if ((tid & 63) == 0) wsum[tid >> 6] = ss;
  __syncthreads();
  float tot = wsum[0] + wsum[1] + wsum[2] + wsum[3];
  float sc = rsqrtf(tot * (1.f / D) + 1e-5f);
  O[(size_t)row * D + tid] = v0 * sc * W[tid];
  O[(size_t)row * D + tid + 256] = v1 * sc * W[tid + 256];
}

// ---------------- mean-pool: partials over 128-t chunks ----------------
__global__ __launch_bounds__(256) void pool_part_kernel(const float* __restrict__ H,
    float* __restrict__ part) {
  int b = blockIdx.x, dg = blockIdx.y, tc = blockIdx.z;   // 4 x 4 x 8
  int tid = threadIdx.x;
  int d = dg * 128 + (tid & 127);
  int ph = tid >> 7;
  const float* base = H + ((size_t)(b * Lseq + tc * 128 + ph * 64)) * Dmodel + d;
  float s = 0.f;
#pragma unroll 8
  for (int t = 0; t < 64; ++t) s += base[(size_t)t * Dmodel];
  __shared__ float red[256];
  red[tid] = s; __syncthreads();
  if (ph == 0)
    part[(size_t)(b * 8 + tc) * Dmodel + d] = red[tid] + red[tid + 128];
}

__global__ __launch_bounds__(256) void pool_fin_kernel(const float* __restrict__ part,
    float* __restrict__ pooled) {
  int i = blockIdx.x * 256 + threadIdx.x;   // over 4*512
  int b = i >> 9, d = i & 511;
  float s = 0.f;
#pragma unroll
  for (int tc = 0; tc < 8; ++tc) s += part[(size_t)(b * 8 + tc) * Dmodel + d];
  pooled[i] = s * (1.f / Lseq);
}

// ---------------- tanh + fc head: one block per output ----------------
__global__ __launch_bounds__(256) void head_kernel(const float* __restrict__ pooled,
    const float* __restrict__ fcw, const float* __restrict__ fcb,
    float* __restrict__ out) {
  int b = blockIdx.x >> 1, j = blockIdx.x & 1;
  int tid = threadIdx.x;
  float s = 0.f;
  for (int d = tid; d < Dmodel; d += 256)
    s += tanhf(pooled[b * Dmodel + d]) * fcw[j * Dmodel + d];
#pragma unroll
  for (int o = 32; o >= 1; o >>= 1) s += __shfl_xor(s, o);
  __shared__ float w[4];
  if ((tid & 63) == 0) w[tid >> 6] = s;
  __syncthreads();
  if (tid == 0) out[b * 2 + j] = w[0] + w[1] + w[2] + w[3] + fcb[j];
}

extern "C" void kernel_launch(void* const* d_in, const int* in_sizes, int n_in,
                              void* d_out, int out_size, void* d_ws, size_t ws_size,
                              hipStream_t stream) {
  const int*   x      = (const int*)d_in[0];
  const float* emb    = (const float*)d_in[1];
  const float* norm_w = (const float*)d_in[2];
  const float* in_w   = (const float*)d_in[3];
  const float* conv_w = (const float*)d_in[4];
  const float* conv_b = (const float*)d_in[5];
  const float* xp_w   = (const float*)d_in[6];
  const float* dtp_w  = (const float*)d_in[7];
  const float* dtp_b  = (const float*)d_in[8];
  const float* A_log  = (const float*)d_in[9];
  const float* Dp     = (const float*)d_in[10];
  const float* out_w  = (const float*)d_in[11];
  const float* fc_w   = (const float*)d_in[12];
  const float* fc_b   = (const float*)d_in[13];
  float* out = (float*)d_out;

  float* ws   = (float*)d_ws;
  float* XZ   = ws;                                  // BLQ*2*DI      (32 MB)
  float* XC   = XZ  + (size_t)BLQ * 2 * DI;          // BLQ*DI        (16 MB)
  float* DTb  = XC  + (size_t)BLQ * DI;              // BLQ*DI        (16 MB)
  float* DBC  = DTb + (size_t)BLQ * DI;              // BLQ*64        (1 MB)
  float* DBCP = DBC + (size_t)BLQ * 64;              // 8*BLQ*64      (8 MB)
  float* H    = DBCP + (size_t)8 * BLQ * 64;         // BLQ*Dmodel    (8 MB)
  float* H2   = H   + (size_t)BLQ * Dmodel;          // BLQ*Dmodel    (8 MB)
  float* POOL = H2  + (size_t)BLQ * Dmodel;          // Bsz*Dmodel
  float* AN   = POOL + Bsz * Dmodel;                 // DI*NST        (64 KB)
  float* PPART = AN + DI * NST;                      // 4*8*512       (64 KB)

  // scan scratch aliases (dead regions during the scan):
  float* YP   = H;      // p1 writes, p3 reads; dead after p3
  float* HEND = DBCP;

  // split-bf16 aliases (all in regions dead at their live ranges):
  ushort* AhI = (ushort*)DBCP;                 // 4096x512  (4MB)
  ushort* AlI = AhI + (size_t)BLQ * Dmodel;    // 4MB  (DBCP = 8MB total)
  ushort* BhI = (ushort*)H2;                   // 2048x512  (2MB)
  ushort* BlI = BhI + (size_t)2 * DI * Dmodel; // 2MB  (H2 = 8MB)
  ushort* AhO = (ushort*)DBCP;                 // 4096x1024 (8MB, exact)
  ushort* AlO = (ushort*)H;                    // 8MB, exact (H dead post-p3)
  ushort* BhO = (ushort*)XZ;                   // 512x1024  (1MB; XZ dead post-p3)
  ushort* BlO = BhO + (size_t)Dmodel * DI;     // 1MB

  embed_kernel<<<BLQ * Dmodel / 1024, 256, 0, stream>>>(x, emb, H);

  for (int l = 0; l < NLAYERS; ++l) {
    const float* inw = in_w  + (size_t)l * 2 * DI * Dmodel;
    const float* cw  = conv_w + (size_t)l * DI * 3;
    const float* cb  = conv_b + (size_t)l * DI;
    const float* xpw = xp_w  + (size_t)l * 64 * DI;
    const float* dtw = dtp_w + (size_t)l * DI * RNK;
    const float* dtb = dtp_b + (size_t)l * DI;
    const float* Al  = A_log + (size_t)l * DI * NST;
    const float* dpl = Dp    + (size_t)l * DI;
    const float* ow  = out_w + (size_t)l * Dmodel * DI;
    const float* nw  = norm_w + (size_t)l * Dmodel;

    // xz = h @ in_w^T : M=4096, N=2048, K=512 (split-bf16 MFMA)
    cvt_frag_kernel<512><<<BLQ * Dmodel / 8 / 256, 256, 0, stream>>>(H, AhI, AlI);
    cvt_frag_kernel<512><<<2 * DI * Dmodel / 8 / 256, 256, 0, stream>>>(inw, BhI, BlI);
    gemm_mfma<<<dim3(2 * DI / 128, BLQ / 128), 256, 0, stream>>>(
        AhI, AlI, BhI, BlI, XZ, 2 * DI, Dmodel);

    // xc = silu(causal depthwise conv(xi))
    conv_silu_kernel<<<BLQ * DI / 256, 256, 0, stream>>>(XZ, cw, cb, XC);

    // dbc = xc @ xp_w^T : M=4096, N=64, K=1024 -- split-K (vector fp32)
    gemm_nt<128, 64, 32, 8, 4, 0><<<dim3(1, BLQ / 128, 8), 256, 0, stream>>>(
        XC, DI, xpw, DI, DBCP, 64, DI / 8, (size_t)BLQ * 64, nullptr);
    reduce8_kernel<<<BLQ * 64 / 256, 256, 0, stream>>>(DBCP, DBC, BLQ * 64, BLQ * 64);

    // dt = softplus(dbc[:, :32] @ dtp_w^T + dtp_b)
    gemm_nt<128, 64, 32, 8, 4, 1><<<dim3(DI / 64, BLQ / 128, 1), 256, 0, stream>>>(
        DBC, 64, dtw, RNK, DTb, DI, RNK, 0, dtb);

    // chunked selective scan + fused epilogue
    an_prep_kernel<<<DI * NST / 256, 256, 0, stream>>>(Al, AN);
    scan_p1_kernel<<<dim3(DI / 256, NCH, Bsz), 256, 0, stream>>>(
        DTb, XC, DBC, AN, YP, HEND);
    scan_p2_kernel<<<Bsz * DI * NST / 256, 256, 0, stream>>>(HEND, DTb, AN);
    scan_p3_kernel<<<BLQ * DI / 256, 256, 0, stream>>>(
        XC, YP, DTb, HEND, DBC, XZ, AN, dpl);

    // h2 = y @ out_w^T : M=4096, N=512, K=1024 (split-bf16 MFMA)
    cvt_frag_kernel<1024><<<BLQ * DI / 8 / 256, 256, 0, stream>>>(XC, AhO, AlO);
    cvt_frag_kernel<1024><<<Dmodel * DI / 8 / 256, 256, 0, stream>>>(ow, BhO, BlO);
    gemm_mfma<<<dim3(Dmodel / 128, BLQ / 128), 256, 0, stream>>>(
        AhO, AlO, BhO, BlO, H2, Dmodel, DI);

    // h = rmsnorm(h2)
    rmsnorm_kernel<<<BLQ, 256, 0, stream>>>(H2, nw, H);
  }

  pool_part_kernel<<<dim3(Bsz, Dmodel / 128, 8), 256, 0, stream>>>(H, PPART);
  pool_fin_kernel<<<Bsz * Dmodel / 256, 256, 0, stream>>>(PPART, POOL);
  head_kernel<<<2 * Bsz, 256, 0, stream>>>(POOL, fc_w, fc_b, out);
}

// Round 5
// 345.601 us; speedup vs baseline: 3.3721x; 1.2840x over previous
//
#include <hip/hip_runtime.h>
#include <math.h>

constexpr int Bsz = 4, Lseq = 1024, Dmodel = 512, NLAYERS = 2;
constexpr int DI = 1024, NST = 16, RNK = 32;
constexpr int BLQ = Bsz * Lseq; // 4096 rows
constexpr int NCH = 32, CLEN = 32; // chunked scan: 32 chunks x 32 steps

typedef __attribute__((ext_vector_type(8))) short short8v;   // 8 bf16
typedef __attribute__((ext_vector_type(8))) unsigned short ushort8v;
typedef __attribute__((ext_vector_type(4))) float f32x4;
typedef unsigned short ushort;

__device__ inline ushort bf16_rne(float v) {
  unsigned u = __float_as_uint(v);
  u += 0x7FFFu + ((u >> 16) & 1u);
  return (ushort)(u >> 16);
}

// fragment address for element (row, k) in a K-col matrix (KT = K/64):
// chunk layout per (rt,kt): [kk(2)][msub(8)][lane(64)][8]
__device__ inline size_t frag_off(int row, int k, int KT) {
  int kt = k >> 6, kk = (k >> 5) & 1, k8 = (k >> 3) & 3;
  int lanei = (row & 15) | (k8 << 4), msub = (row >> 4) & 7, rt = row >> 7;
  return ((((size_t)(rt * KT + kt) * 2 + kk) * 8 + msub) * 64 + lanei) * 8;
}

// ---------------- embedding gather + A-fragment emit (K=512) ----------------
__global__ __launch_bounds__(256) void embed_kernel(const int* __restrict__ x,
    const float* __restrict__ emb, float* __restrict__ H, ushort* __restrict__ Af) {
  int i = blockIdx.x * 256 + threadIdx.x;        // 8 floats per thread
  int row = i >> 6, j = i & 63, k = j * 8;
  int tok = x[row];
  const float* src = &emb[(size_t)tok * Dmodel + k];
  float4 v0 = *reinterpret_cast<const float4*>(src);
  float4 v1 = *reinterpret_cast<const float4*>(src + 4);
  float* dst = &H[(size_t)row * Dmodel + k];
  *reinterpret_cast<float4*>(dst) = v0;
  *reinterpret_cast<float4*>(dst + 4) = v1;
  float xs[8] = {v0.x, v0.y, v0.z, v0.w, v1.x, v1.y, v1.z, v1.w};
  ushort hv[8];
#pragma unroll
  for (int e = 0; e < 8; ++e) hv[e] = bf16_rne(xs[e]);
  *reinterpret_cast<ushort8v*>(&Af[frag_off(row, k, 8)]) =
      *reinterpret_cast<ushort8v*>(hv);
}

// ---------------- fp32 -> split bf16 (hi/lo), fragment-tiled (weights) -------
template<int K>
__global__ __launch_bounds__(256) void cvt_frag_kernel(
    const float* __restrict__ X, ushort* __restrict__ Xh, ushort* __restrict__ Xl)
{
  constexpr int K8 = K / 8, KT = K / 64;
  int linear = blockIdx.x * 256 + threadIdx.x;
  int row = linear / K8;
  int k = (linear - row * K8) * 8;
  const float* src = X + (size_t)row * K + k;
  float4 v0 = *reinterpret_cast<const float4*>(src);
  float4 v1 = *reinterpret_cast<const float4*>(src + 4);
  float xs[8] = {v0.x, v0.y, v0.z, v0.w, v1.x, v1.y, v1.z, v1.w};
  ushort hs[8], ls[8];
#pragma unroll
  for (int j = 0; j < 8; ++j) {
    unsigned u = __float_as_uint(xs[j]);
    float hf = __uint_as_float(u & 0xFFFF0000u);
    float r = xs[j] - hf;                        // exact residual
    hs[j] = (ushort)(u >> 16);
    ls[j] = (ushort)(__float_as_uint(r) >> 16);
  }
  size_t d = frag_off(row, k, KT);
  *reinterpret_cast<ushort8v*>(&Xh[d]) = *reinterpret_cast<ushort8v*>(hs);
  *reinterpret_cast<ushort8v*>(&Xl[d]) = *reinterpret_cast<ushort8v*>(ls);
}

// ---------------- MFMA GEMM: A single-bf16, B split hi/lo --------------------
// C[m,n] = sum_k A[m,k]*B[n,k]; BM=BN=128, BK=64; 4 waves (2x2); 2 MFMA/tile.
__global__ __launch_bounds__(256) void gemm_mfma(
    const ushort* __restrict__ Ah,
    const ushort* __restrict__ Bh, const ushort* __restrict__ Bl,
    float* __restrict__ C, int N, int K)
{
  const int KT = K >> 6;
  constexpr int ASZ = 2 * 8 * 64 * 8;   // 8192 ushorts = 16KB per array
  __shared__ ushort lds[3 * ASZ];       // Ah | Bh | Bl

  const int tid = threadIdx.x;
  const int lane = tid & 63, wid = tid >> 6;
  const int wm = wid >> 1, wn = wid & 1;
  const int bm0 = blockIdx.y * 128, bn0 = blockIdx.x * 128;
  const size_t abase = (size_t)blockIdx.y * KT * ASZ;
  const size_t bbase = (size_t)blockIdx.x * KT * ASZ;

  // wave0 stages Ah, wave1 Bh, wave2 Bl, wave3 idle (loads are async DMA)
  const ushort* gsrc = (wid == 0) ? Ah : (wid == 1) ? Bh : Bl;
  const size_t gb = (wid == 0) ? abase : bbase;

  f32x4 acc[4][4];
#pragma unroll
  for (int i = 0; i < 4; ++i)
#pragma unroll
    for (int j = 0; j < 4; ++j) acc[i][j] = (f32x4){0.f, 0.f, 0.f, 0.f};

  const int msel = wm * 4, nsel = wn * 4;

  for (int kt = 0; kt < KT; ++kt) {
    if (wid < 3) {
      const ushort* sbase = gsrc + gb + (size_t)kt * ASZ + lane * 8;
#pragma unroll
      for (int i = 0; i < 16; ++i) {
        __builtin_amdgcn_global_load_lds(
            (const __attribute__((address_space(1))) void*)(sbase + i * 512),
            (__attribute__((address_space(3))) void*)(lds + wid * ASZ + i * 512),
            16, 0, 0);
      }
    }
    __syncthreads();
#pragma unroll
    for (int kk = 0; kk < 2; ++kk) {
      short8v a_h[4], b_h[4], b_l[4];
#pragma unroll
      for (int i = 0; i < 4; ++i) {
        int ai = ((kk * 8 + msel + i) * 64 + lane) * 8;
        int bi = ((kk * 8 + nsel + i) * 64 + lane) * 8;
        a_h[i] = *reinterpret_cast<const short8v*>(&lds[0 * ASZ + ai]);
        b_h[i] = *reinterpret_cast<const short8v*>(&lds[1 * ASZ + bi]);
        b_l[i] = *reinterpret_cast<const short8v*>(&lds[2 * ASZ + bi]);
      }
#pragma unroll
      for (int ms = 0; ms < 4; ++ms)
#pragma unroll
        for (int ns = 0; ns < 4; ++ns) {
          acc[ms][ns] = __builtin_amdgcn_mfma_f32_16x16x32_bf16(a_h[ms], b_h[ns], acc[ms][ns], 0, 0, 0);
          acc[ms][ns] = __builtin_amdgcn_mfma_f32_16x16x32_bf16(a_h[ms], b_l[ns], acc[ms][ns], 0, 0, 0);
        }
    }
    __syncthreads();
  }

  const int cr = lane >> 4, cc = lane & 15;
#pragma unroll
  for (int ms = 0; ms < 4; ++ms) {
    int row0 = bm0 + (msel + ms) * 16 + cr * 4;
#pragma unroll
    for (int ns = 0; ns < 4; ++ns) {
      int col = bn0 + (nsel + ns) * 16 + cc;
#pragma unroll
      for (int r = 0; r < 4; ++r)
        C[(size_t)(row0 + r) * N + col] = acc[ms][ns][r];
    }
  }
}

// ---------------- generic NT GEMM (fp32 vector), small GEMMs ----------------
template<int BM, int BN, int BK, int TM, int TN, int EPI>
__global__ __launch_bounds__(256) void gemm_nt(
    const float* __restrict__ A, int lda,
    const float* __restrict__ B, int ldb,
    float* __restrict__ C, int ldc,
    int klen, size_t cslice, const float* __restrict__ bias)
{
  constexpr int NTX = BN / TN;
  constexpr int NTY = BM / TM;
  static_assert(NTX * NTY == 256, "thread count");
  static_assert(TN == 4, "float4 stores");
  __shared__ float As[BK][BM + 4];
  __shared__ float Bs[BK][BN + 4];
  const int bn0 = blockIdx.x * BN;
  const int bm0 = blockIdx.y * BM;
  const int kbeg = blockIdx.z * klen;
  const int tid = threadIdx.x;
  const int tx = tid % NTX, ty = tid / NTX;
  float acc[TM][TN] = {};
  for (int kt = kbeg; kt < kbeg + klen; kt += BK) {
#pragma unroll
    for (int i = 0; i < BM * BK / 1024; ++i) {
      int idx = (tid + i * 256) * 4;
      int m = idx / BK, k = idx % BK;
      float4 v = *reinterpret_cast<const float4*>(&A[(size_t)(bm0 + m) * lda + kt + k]);
      As[k + 0][m] = v.x; As[k + 1][m] = v.y; As[k + 2][m] = v.z; As[k + 3][m] = v.w;
    }
#pragma unroll
    for (int i = 0; i < BN * BK / 1024; ++i) {
      int idx = (tid + i * 256) * 4;
      int n = idx / BK, k = idx % BK;
      float4 v = *reinterpret_cast<const float4*>(&B[(size_t)(bn0 + n) * ldb + kt + k]);
      Bs[k + 0][n] = v.x; Bs[k + 1][n] = v.y; Bs[k + 2][n] = v.z; Bs[k + 3][n] = v.w;
    }
    __syncthreads();
#pragma unroll
    for (int k = 0; k < BK; ++k) {
      float a[TM], b[TN];
#pragma unroll
      for (int i = 0; i < TM; i += 4)
        *reinterpret_cast<float4*>(&a[i]) = *reinterpret_cast<const float4*>(&As[k][ty * TM + i]);
#pragma unroll
      for (int j = 0; j < TN; j += 4)
        *reinterpret_cast<float4*>(&b[j]) = *reinterpret_cast<const float4*>(&Bs[k][tx * TN + j]);
#pragma unroll
      for (int i = 0; i < TM; ++i)
#pragma unroll
        for (int j = 0; j < TN; ++j)
          acc[i][j] = fmaf(a[i], b[j], acc[i][j]);
    }
    __syncthreads();
  }
  float* Cw = C + (size_t)blockIdx.z * cslice;
#pragma unroll
  for (int i = 0; i < TM; ++i) {
    int m = bm0 + ty * TM + i;
    float vv[4];
#pragma unroll
    for (int j = 0; j < TN; ++j) {
      float v = acc[i][j];
      if (EPI == 1) {
        v += bias[bn0 + tx * TN + j];
        v = (v > 15.f) ? v : log1pf(__expf(v));
      }
      vv[j] = v;
    }
    *reinterpret_cast<float4*>(&Cw[(size_t)m * ldc + bn0 + tx * TN]) =
        *reinterpret_cast<float4*>(vv);
  }
}

// ---------------- reduce 8 split-K partial slices ----------------
__global__ __launch_bounds__(256) void reduce8_kernel(const float* __restrict__ P,
    float* __restrict__ O, int n, int slice) {
  int i = blockIdx.x * 256 + threadIdx.x;
  if (i >= n) return;
  float s = 0.f;
#pragma unroll
  for (int j = 0; j < 8; ++j) s += P[(size_t)j * slice + i];
  O[i] = s;
}

// ---------------- depthwise causal conv (dc=3) + silu ----------------
__global__ __launch_bounds__(256) void conv_silu_kernel(
    const float* __restrict__ XZ, const float* __restrict__ cw,
    const float* __restrict__ cb, float* __restrict__ XC)
{
  int idx = blockIdx.x * 256 + threadIdx.x;   // over BLQ*DI
  int d = idx % DI;
  int bl = idx / DI;
  int l = bl % Lseq;
  size_t base = (size_t)bl * (2 * DI) + d;    // xi = XZ[..., 0:DI]
  float acc = cb[d];
  float w0 = cw[d * 3], w1 = cw[d * 3 + 1], w2 = cw[d * 3 + 2];
  if (l >= 2) acc = fmaf(XZ[base - 2 * (size_t)(2 * DI)], w0, acc);
  if (l >= 1) acc = fmaf(XZ[base - (size_t)(2 * DI)], w1, acc);
  acc = fmaf(XZ[base], w2, acc);
  XC[idx] = acc / (1.f + __expf(-acc));       // silu
}

// ---------------- A = -exp(A_log) precompute ----------------
__global__ __launch_bounds__(256) void an_prep_kernel(const float* __restrict__ Al,
    float* __restrict__ AN) {
  int i = blockIdx.x * 256 + threadIdx.x;
  AN[i] = -expf(Al[i]);
}

// ---------------- scan phase 1: chunk-end states + chunk dt-sums ------------
__global__ __launch_bounds__(256) void scan_p1_kernel(
    const float* __restrict__ DTb, const float* __restrict__ XC,
    const float* __restrict__ DBC, const float* __restrict__ AN,
    float* __restrict__ HEND, float* __restrict__ DSUM)
{
  const int d = blockIdx.x * 256 + threadIdx.x;
  const int c = blockIdx.y, b = blockIdx.z;
  const int t0 = b * Lseq + c * CLEN;
  __shared__ float Bs[CLEN][16];
#pragma unroll
  for (int i = 0; i < 2; ++i) {
    int e = threadIdx.x + i * 256;
    Bs[e >> 4][e & 15] = DBC[(size_t)(t0 + (e >> 4)) * 64 + 32 + (e & 15)];
  }
  float An[16];
#pragma unroll
  for (int j = 0; j < 4; ++j)
    *reinterpret_cast<float4*>(&An[j * 4]) =
        *reinterpret_cast<const float4*>(&AN[d * 16 + j * 4]);
  __syncthreads();
  float h[16] = {};
  float S = 0.f;
  for (int t = 0; t < CLEN; ++t) {
    size_t g = (size_t)(t0 + t) * DI + d;
    float dt = DTb[g], xc = XC[g];
    S += dt;
    float dtxc = dt * xc;
#pragma unroll
    for (int n = 0; n < 16; ++n)
      h[n] = fmaf(__expf(An[n] * dt), h[n], dtxc * Bs[t][n]);
  }
  size_t hb = ((size_t)(b * NCH + c) * DI + d) * 16;
#pragma unroll
  for (int j = 0; j < 4; ++j)
    *reinterpret_cast<float4*>(&HEND[hb + j * 4]) =
        *reinterpret_cast<float4*>(&h[j * 4]);
  DSUM[(size_t)(b * NCH + c) * DI + d] = S;
}

// ---------------- scan phase 2: combine; HEND -> chunk-initial states -------
__global__ __launch_bounds__(256) void scan_p2_kernel(
    float* __restrict__ HEND, const float* __restrict__ DSUM,
    const float* __restrict__ AN)
{
  int id = blockIdx.x * 256 + threadIdx.x;   // (b,d,n)
  int n = id & 15, d = (id >> 4) & (DI - 1), b = id >> 14;
  float An = AN[d * 16 + n];
  float hg = 0.f;
  for (int c = 0; c < NCH; ++c) {
    size_t hi = ((size_t)(b * NCH + c) * DI + d) * 16 + n;
    float hl = HEND[hi];
    float Dc = DSUM[(size_t)(b * NCH + c) * DI + d];
    HEND[hi] = hg;
    hg = fmaf(__expf(An * Dc), hg, hl);
  }
}

// ---------------- scan phase 3: exact recompute + epilogue + A-frag out -----
// grid (DI/256, NCH, Bsz); emits out-proj A fragments (K=1024) in bf16 RNE.
__global__ __launch_bounds__(256) void scan_p3_kernel(
    const float* __restrict__ XC, const float* __restrict__ DTb,
    const float* __restrict__ DBC, const float* __restrict__ XZ,
    const float* __restrict__ HEND, const float* __restrict__ AN,
    const float* __restrict__ Dp, ushort* __restrict__ Af)
{
  const int tid = threadIdx.x;
  const int dg = blockIdx.x, c = blockIdx.y, b = blockIdx.z;
  const int d = dg * 256 + tid;
  const int t0 = b * Lseq + c * CLEN;    // global row base (bt)
  __shared__ float BC[CLEN][32];
  __shared__ float ys[CLEN][264];
#pragma unroll
  for (int i = 0; i < 4; ++i) {
    int e = tid + i * 256;
    BC[e >> 5][e & 31] = DBC[(size_t)(t0 + (e >> 5)) * 64 + 32 + (e & 31)];
  }
  float An[16], h[16];
  size_t hb = ((size_t)(b * NCH + c) * DI + d) * 16;
#pragma unroll
  for (int j = 0; j < 4; ++j) {
    *reinterpret_cast<float4*>(&An[j * 4]) =
        *reinterpret_cast<const float4*>(&AN[d * 16 + j * 4]);
    *reinterpret_cast<float4*>(&h[j * 4]) =
        *reinterpret_cast<const float4*>(&HEND[hb + j * 4]);   // h_init
  }
  float Dpv = Dp[d];
  __syncthreads();
  for (int t = 0; t < CLEN; ++t) {
    size_t g = (size_t)(t0 + t) * DI + d;
    float dt = DTb[g], xc = XC[g];
    float z = XZ[(size_t)(t0 + t) * (2 * DI) + DI + d];
    float dtxc = dt * xc;
    float y = 0.f;
#pragma unroll
    for (int n = 0; n < 16; ++n) {
      h[n] = fmaf(__expf(An[n] * dt), h[n], dtxc * BC[t][n]);
      y = fmaf(h[n], BC[t][16 + n], y);
    }
    float sil = z / (1.f + __expf(-z));
    ys[t][tid] = (y + xc * Dpv) * sil;
  }
  __syncthreads();
  // fragment emit: 4 ushort8 units per thread
#pragma unroll
  for (int i = 0; i < 4; ++i) {
    int u = tid + i * 256;          // 0..1023
    int tt = u >> 5, j8 = u & 31;
    int row = t0 + tt;
    int kg = dg * 256 + j8 * 8;
    ushort hv[8];
#pragma unroll
    for (int e = 0; e < 8; ++e) hv[e] = bf16_rne(ys[tt][j8 * 8 + e]);
    *reinterpret_cast<ushort8v*>(&Af[frag_off(row, kg, 16)]) =
        *reinterpret_cast<ushort8v*>(hv);
  }
}

// ---------------- rmsnorm + A-fragment emit (K=512) ----------------
// block = 4 rows x 64 lanes; one wave per row.
__global__ __launch_bounds__(256) void rmsnorm_kernel(const float* __restrict__ X,
    const float* __restrict__ W, float* __restrict__ O, ushort* __restrict__ Af) {
  int row = blockIdx.x * 4 + (threadIdx.x >> 6);
  int lane = threadIdx.x & 63;
  int k = lane * 8;
  const float* xp = X + (size_t)row * Dmodel + k;
  float4 v0 = *reinterpret_cast<const float4*>(xp);
  float4 v1 = *reinterpret_cast<const float4*>(xp + 4);
  float vs[8] = {v0.x, v0.y, v0.z, v0.w, v1.x, v1.y, v1.z, v1.w};
  float ss = 0.f;
#pragma unroll
  for (int e = 0; e < 8; ++e) ss = fmaf(vs[e], vs[e], ss);
#pragma unroll
  for (int o = 32; o >= 1; o >>= 1) ss += __shfl_xor(ss, o);
  float sc = rsqrtf(ss * (1.f / Dmodel) + 1e-5f);
  const float* wp = W + k;
  float4 w0 = *reinterpret_cast<const float4*>(wp);
  float4 w1 = *reinterpret_cast<const float4*>(wp + 4);
  float wsv[8] = {w0.x, w0.y, w0.z, w0.w, w1.x, w1.y, w1.z, w1.w};
  float os[8];
  ushort hv[8];
#pragma unroll
  for (int e = 0; e < 8; ++e) {
    os[e] = vs[e] * sc * wsv[e];
    hv[e] = bf16_rne(os[e]);
  }
  float* op = O + (size_t)row * Dmodel + k;
  *reinterpret_cast<float4*>(op) = *reinterpret_cast<float4*>(&os[0]);
  *reinterpret_cast<float4*>(op + 4) = *reinterpret_cast<float4*>(&os[4]);
  *reinterpret_cast<ushort8v*>(&Af[frag_off(row, k, 8)]) =
      *reinterpret_cast<ushort8v*>(hv);
}

// ---------------- mean-pool: partials over 128-t chunks ----------------
__global__ __launch_bounds__(256) void pool_part_kernel(const float* __restrict__ H,
    float* __restrict__ part) {
  int b = blockIdx.x, dg = blockIdx.y, tc = blockIdx.z;   // 4 x 4 x 8
  int tid = threadIdx.x;
  int d = dg * 128 + (tid & 127);
  int ph = tid >> 7;
  const float* base = H + ((size_t)(b * Lseq + tc * 128 + ph * 64)) * Dmodel + d;
  float s = 0.f;
#pragma unroll 8
  for (int t = 0; t < 64; ++t) s += base[(size_t)t * Dmodel];
  __shared__ float red[256];
  red[tid] = s; __syncthreads();
  if (ph == 0)
    part[(size_t)(b * 8 + tc) * Dmodel + d] = red[tid] + red[tid + 128];
}

__global__ __launch_bounds__(256) void pool_fin_kernel(const float* __restrict__ part,
    float* __restrict__ pooled) {
  int i = blockIdx.x * 256 + threadIdx.x;   // over 4*512
  int b = i >> 9, d = i & 511;
  float s = 0.f;
#pragma unroll
  for (int tc = 0; tc < 8; ++tc) s += part[(size_t)(b * 8 + tc) * Dmodel + d];
  pooled[i] = s * (1.f / Lseq);
}

// ---------------- tanh + fc head: one block per output ----------------
__global__ __launch_bounds__(256) void head_kernel(const float* __restrict__ pooled,
    const float* __restrict__ fcw, const float* __restrict__ fcb,
    float* __restrict__ out) {
  int b = blockIdx.x >> 1, j = blockIdx.x & 1;
  int tid = threadIdx.x;
  float s = 0.f;
  for (int d = tid; d < Dmodel; d += 256)
    s += tanhf(pooled[b * Dmodel + d]) * fcw[j * Dmodel + d];
#pragma unroll
  for (int o = 32; o >= 1; o >>= 1) s += __shfl_xor(s, o);
  __shared__ float w[4];
  if ((tid & 63) == 0) w[tid >> 6] = s;
  __syncthreads();
  if (tid == 0) out[b * 2 + j] = w[0] + w[1] + w[2] + w[3] + fcb[j];
}

extern "C" void kernel_launch(void* const* d_in, const int* in_sizes, int n_in,
                              void* d_out, int out_size, void* d_ws, size_t ws_size,
                              hipStream_t stream) {
  const int*   x      = (const int*)d_in[0];
  const float* emb    = (const float*)d_in[1];
  const float* norm_w = (const float*)d_in[2];
  const float* in_w   = (const float*)d_in[3];
  const float* conv_w = (const float*)d_in[4];
  const float* conv_b = (const float*)d_in[5];
  const float* xp_w   = (const float*)d_in[6];
  const float* dtp_w  = (const float*)d_in[7];
  const float* dtp_b  = (const float*)d_in[8];
  const float* A_log  = (const float*)d_in[9];
  const float* Dp     = (const float*)d_in[10];
  const float* out_w  = (const float*)d_in[11];
  const float* fc_w   = (const float*)d_in[12];
  const float* fc_b   = (const float*)d_in[13];
  float* out = (float*)d_out;

  float* ws   = (float*)d_ws;
  float* XZ   = ws;                                  // BLQ*2*DI      (32 MB)
  float* XC   = XZ  + (size_t)BLQ * 2 * DI;          // BLQ*DI        (16 MB)
  float* DTb  = XC  + (size_t)BLQ * DI;              // BLQ*DI        (16 MB)
  float* DBC  = DTb + (size_t)BLQ * DI;              // BLQ*64        (1 MB)
  float* DBCP = DBC + (size_t)BLQ * 64;              // 8*BLQ*64      (8 MB)
  float* H    = DBCP + (size_t)8 * BLQ * 64;         // BLQ*Dmodel    (8 MB)
  float* H2   = H   + (size_t)BLQ * Dmodel;          // BLQ*Dmodel    (8 MB)
  float* POOL = H2  + (size_t)BLQ * Dmodel;          // Bsz*Dmodel    (8 KB)
  float* AN   = POOL + Bsz * Dmodel;                 // DI*NST        (64 KB)
  float* PPART = AN + DI * NST;                      // 4*8*512       (64 KB)
  float* DSUM = PPART + Bsz * 8 * Dmodel;            // Bsz*NCH*DI    (512 KB)

  // aliases (each region dead at the alias's live range):
  float*  HEND = DBCP;                          // 8MB exact; scan p1->p3
  ushort* AhI = (ushort*)DBCP;                  // 4MB; written by embed/rmsnorm,
                                                // read by gemm_in, then DBCP reused
  ushort* BhI = (ushort*)H2;                    // 2MB; H2 dead until gemm_out
  ushort* BlI = BhI + (size_t)2 * DI * Dmodel;  // 2MB
  ushort* AhO = (ushort*)H;                     // 8MB exact; H dead during layer
  ushort* BhO = (ushort*)XZ;                    // 1MB; XZ dead after scan_p3
  ushort* BlO = BhO + (size_t)Dmodel * DI;      // 1MB

  embed_kernel<<<BLQ * Dmodel / 8 / 256, 256, 0, stream>>>(x, emb, H, AhI);

  for (int l = 0; l < NLAYERS; ++l) {
    const float* inw = in_w  + (size_t)l * 2 * DI * Dmodel;
    const float* cw  = conv_w + (size_t)l * DI * 3;
    const float* cb  = conv_b + (size_t)l * DI;
    const float* xpw = xp_w  + (size_t)l * 64 * DI;
    const float* dtw = dtp_w + (size_t)l * DI * RNK;
    const float* dtb = dtp_b + (size_t)l * DI;
    const float* Al  = A_log + (size_t)l * DI * NST;
    const float* dpl = Dp    + (size_t)l * DI;
    const float* ow  = out_w + (size_t)l * Dmodel * DI;
    const float* nw  = norm_w + (size_t)l * Dmodel;

    // xz = h @ in_w^T : M=4096, N=2048, K=512
    cvt_frag_kernel<512><<<2 * DI * Dmodel / 8 / 256, 256, 0, stream>>>(inw, BhI, BlI);
    gemm_mfma<<<dim3(2 * DI / 128, BLQ / 128), 256, 0, stream>>>(
        AhI, BhI, BlI, XZ, 2 * DI, Dmodel);

    // xc = silu(causal depthwise conv(xi))
    conv_silu_kernel<<<BLQ * DI / 256, 256, 0, stream>>>(XZ, cw, cb, XC);

    // dbc = xc @ xp_w^T : M=4096, N=64, K=1024 -- split-K (vector fp32)
    gemm_nt<128, 64, 32, 8, 4, 0><<<dim3(1, BLQ / 128, 8), 256, 0, stream>>>(
        XC, DI, xpw, DI, DBCP, 64, DI / 8, (size_t)BLQ * 64, nullptr);
    reduce8_kernel<<<BLQ * 64 / 256, 256, 0, stream>>>(DBCP, DBC, BLQ * 64, BLQ * 64);

    // dt = softplus(dbc[:, :32] @ dtp_w^T + dtp_b)
    gemm_nt<128, 64, 32, 8, 4, 1><<<dim3(DI / 64, BLQ / 128, 1), 256, 0, stream>>>(
        DBC, 64, dtw, RNK, DTb, DI, RNK, 0, dtb);

    // chunked selective scan (exact recompute) + fused epilogue + A-frag emit
    an_prep_kernel<<<DI * NST / 256, 256, 0, stream>>>(Al, AN);
    scan_p1_kernel<<<dim3(DI / 256, NCH, Bsz), 256, 0, stream>>>(
        DTb, XC, DBC, AN, HEND, DSUM);
    scan_p2_kernel<<<Bsz * DI * NST / 256, 256, 0, stream>>>(HEND, DSUM, AN);
    scan_p3_kernel<<<dim3(DI / 256, NCH, Bsz), 256, 0, stream>>>(
        XC, DTb, DBC, XZ, HEND, AN, dpl, AhO);

    // h2 = y @ out_w^T : M=4096, N=512, K=1024
    cvt_frag_kernel<1024><<<Dmodel * DI / 8 / 256, 256, 0, stream>>>(ow, BhO, BlO);
    gemm_mfma<<<dim3(Dmodel / 128, BLQ / 128), 256, 0, stream>>>(
        AhO, BhO, BlO, H2, Dmodel, DI);

    // h = rmsnorm(h2) -> fp32 H + next layer's A fragments
    rmsnorm_kernel<<<BLQ / 4, 256, 0, stream>>>(H2, nw, H, AhI);
  }

  pool_part_kernel<<<dim3(Bsz, Dmodel / 128, 8), 256, 0, stream>>>(H, PPART);
  pool_fin_kernel<<<Bsz * Dmodel / 256, 256, 0, stream>>>(PPART, POOL);
  head_kernel<<<2 * Bsz, 256, 0, stream>>>(POOL, fc_w, fc_b, out);
}

// Round 6
// 311.643 us; speedup vs baseline: 3.7396x; 1.1090x over previous
//
#include <hip/hip_runtime.h>
#include <math.h>

constexpr int Bsz = 4, Lseq = 1024, Dmodel = 512, NLAYERS = 2;
constexpr int DI = 1024, NST = 16, RNK = 32;
constexpr int BLQ = Bsz * Lseq;     // 4096 rows
constexpr int NCH = 32, CLEN = 32;  // chunked scan

typedef __attribute__((ext_vector_type(8))) short short8v;
typedef __attribute__((ext_vector_type(8))) unsigned short ushort8v;
typedef __attribute__((ext_vector_type(4))) float f32x4;
typedef unsigned short ushort;

__device__ inline ushort bf16_rne(float v) {
  unsigned u = __float_as_uint(v);
  u += 0x7FFFu + ((u >> 16) & 1u);
  return (ushort)(u >> 16);
}
__device__ inline float bf2f(ushort u) {
  return __uint_as_float(((unsigned)u) << 16);
}
// fragment address for element (row, k); chunk per (rt,kt): [kk(2)][msub(8)][lane(64)][8]
__device__ inline size_t frag_off(int row, int k, int KT) {
  int kt = k >> 6, kk = (k >> 5) & 1, k8 = (k >> 3) & 3;
  int lanei = (row & 15) | (k8 << 4), msub = (row >> 4) & 7, rt = row >> 7;
  return ((((size_t)(rt * KT + kt) * 2 + kk) * 8 + msub) * 64 + lanei) * 8;
}

// ---------------- embedding gather -> A fragments (K=512) ----------------
__global__ __launch_bounds__(256) void embed_kernel(const int* __restrict__ x,
    const float* __restrict__ emb, ushort* __restrict__ Af) {
  int i = blockIdx.x * 256 + threadIdx.x;  // 8 floats/thread
  int row = i >> 6, k = (i & 63) * 8;
  int tok = x[row];
  const float* src = &emb[(size_t)tok * Dmodel + k];
  float4 v0 = *reinterpret_cast<const float4*>(src);
  float4 v1 = *reinterpret_cast<const float4*>(src + 4);
  float xs[8] = {v0.x, v0.y, v0.z, v0.w, v1.x, v1.y, v1.z, v1.w};
  ushort hv[8];
#pragma unroll
  for (int e = 0; e < 8; ++e) hv[e] = bf16_rne(xs[e]);
  *reinterpret_cast<ushort8v*>(&Af[frag_off(row, k, 8)]) =
      *reinterpret_cast<ushort8v*>(hv);
}

// ---------------- ALL weights -> split-bf16 fragments, one kernel ------------
// regions: [0,1024) in_w (2 x 2048 x 512); [1024,1088) xp_w (2 x 64 x 1024);
//          [1088,1600) out_w (2 x 512 x 1024)
__global__ __launch_bounds__(256) void cvtw_kernel(
    const float* __restrict__ in_w, const float* __restrict__ xp_w,
    const float* __restrict__ out_w,
    ushort* __restrict__ WIh, ushort* __restrict__ WIl,
    ushort* __restrict__ XPh, ushort* __restrict__ XPl,
    ushort* __restrict__ WOh, ushort* __restrict__ WOl)
{
  int blk = blockIdx.x;
  const float* src; ushort *dh, *dl; int KT; int row, k;
  if (blk < 1024) {                       // in_w: unit = (l, row<2048, k8<64)
    int u = blk * 256 + threadIdx.x;
    int l = u >> 17, rem = u & 131071;
    row = rem >> 6; k = (rem & 63) * 8; KT = 8;
    src = in_w + (size_t)l * 2048 * 512 + (size_t)row * 512 + k;
    size_t base = (size_t)l * 2048 * 512;
    dh = WIh + base; dl = WIl + base;
  } else if (blk < 1088) {                // xp_w: unit = (l, row<64, k8<128)
    int u = (blk - 1024) * 256 + threadIdx.x;
    int l = u >> 13, rem = u & 8191;
    row = rem >> 7; k = (rem & 127) * 8; KT = 16;
    src = xp_w + (size_t)l * 64 * 1024 + (size_t)row * 1024 + k;
    size_t base = (size_t)l * 131072;     // 16 chunks * 8192 (128-row padded)
    dh = XPh + base; dl = XPl + base;
  } else {                                // out_w: unit = (l, row<512, k8<128)
    int u = (blk - 1088) * 256 + threadIdx.x;
    int l = u >> 16, rem = u & 65535;
    row = rem >> 7; k = (rem & 127) * 8; KT = 16;
    src = out_w + (size_t)l * 512 * 1024 + (size_t)row * 1024 + k;
    size_t base = (size_t)l * 512 * 1024;
    dh = WOh + base; dl = WOl + base;
  }
  float4 v0 = *reinterpret_cast<const float4*>(src);
  float4 v1 = *reinterpret_cast<const float4*>(src + 4);
  float xs[8] = {v0.x, v0.y, v0.z, v0.w, v1.x, v1.y, v1.z, v1.w};
  ushort hs[8], ls[8];
#pragma unroll
  for (int j = 0; j < 8; ++j) {
    unsigned u = __float_as_uint(xs[j]);
    float hf = __uint_as_float(u & 0xFFFF0000u);
    float r = xs[j] - hf;
    hs[j] = (ushort)(u >> 16);
    ls[j] = (ushort)(__float_as_uint(r) >> 16);
  }
  size_t d = frag_off(row, k, KT);
  *reinterpret_cast<ushort8v*>(&dh[d]) = *reinterpret_cast<ushort8v*>(hs);
  *reinterpret_cast<ushort8v*>(&dl[d]) = *reinterpret_cast<ushort8v*>(ls);
}

// ---------------- MFMA GEMM: A bf16, B split hi/lo; OB: 0=f32 out, 1=bf16 ----
template<int OB>
__global__ __launch_bounds__(256) void gemm_mfma(
    const ushort* __restrict__ Ah,
    const ushort* __restrict__ Bh, const ushort* __restrict__ Bl,
    void* __restrict__ Cv, int N, int K)
{
  const int KT = K >> 6;
  constexpr int ASZ = 2 * 8 * 64 * 8;   // 8192 ushorts = 16KB
  __shared__ ushort lds[3 * ASZ];
  const int tid = threadIdx.x;
  const int lane = tid & 63, wid = tid >> 6;
  const int wm = wid >> 1, wn = wid & 1;
  const int bm0 = blockIdx.y * 128, bn0 = blockIdx.x * 128;
  const size_t abase = (size_t)blockIdx.y * KT * ASZ;
  const size_t bbase = (size_t)blockIdx.x * KT * ASZ;
  const ushort* gsrc = (wid == 0) ? Ah : (wid == 1) ? Bh : Bl;
  const size_t gb = (wid == 0) ? abase : bbase;
  f32x4 acc[4][4];
#pragma unroll
  for (int i = 0; i < 4; ++i)
#pragma unroll
    for (int j = 0; j < 4; ++j) acc[i][j] = (f32x4){0.f, 0.f, 0.f, 0.f};
  const int msel = wm * 4, nsel = wn * 4;
  for (int kt = 0; kt < KT; ++kt) {
    if (wid < 3) {
      const ushort* sbase = gsrc + gb + (size_t)kt * ASZ + lane * 8;
#pragma unroll
      for (int i = 0; i < 16; ++i)
        __builtin_amdgcn_global_load_lds(
            (const __attribute__((address_space(1))) void*)(sbase + i * 512),
            (__attribute__((address_space(3))) void*)(lds + wid * ASZ + i * 512),
            16, 0, 0);
    }
    __syncthreads();
#pragma unroll
    for (int kk = 0; kk < 2; ++kk) {
      short8v a_h[4], b_h[4], b_l[4];
#pragma unroll
      for (int i = 0; i < 4; ++i) {
        int ai = ((kk * 8 + msel + i) * 64 + lane) * 8;
        int bi = ((kk * 8 + nsel + i) * 64 + lane) * 8;
        a_h[i] = *reinterpret_cast<const short8v*>(&lds[0 * ASZ + ai]);
        b_h[i] = *reinterpret_cast<const short8v*>(&lds[1 * ASZ + bi]);
        b_l[i] = *reinterpret_cast<const short8v*>(&lds[2 * ASZ + bi]);
      }
#pragma unroll
      for (int ms = 0; ms < 4; ++ms)
#pragma unroll
        for (int ns = 0; ns < 4; ++ns) {
          acc[ms][ns] = __builtin_amdgcn_mfma_f32_16x16x32_bf16(a_h[ms], b_h[ns], acc[ms][ns], 0, 0, 0);
          acc[ms][ns] = __builtin_amdgcn_mfma_f32_16x16x32_bf16(a_h[ms], b_l[ns], acc[ms][ns], 0, 0, 0);
        }
    }
    __syncthreads();
  }
  const int cr = lane >> 4, cc = lane & 15;
#pragma unroll
  for (int ms = 0; ms < 4; ++ms) {
    int row0 = bm0 + (msel + ms) * 16 + cr * 4;
#pragma unroll
    for (int ns = 0; ns < 4; ++ns) {
      int col = bn0 + (nsel + ns) * 16 + cc;
#pragma unroll
      for (int r = 0; r < 4; ++r) {
        if (OB) ((ushort*)Cv)[(size_t)(row0 + r) * N + col] = bf16_rne(acc[ms][ns][r]);
        else    ((float*)Cv)[(size_t)(row0 + r) * N + col] = acc[ms][ns][r];
      }
    }
  }
}

// ---------------- xp MFMA GEMM: M=4096 N=64 K=1024, split-K z=2 --------------
__global__ __launch_bounds__(256) void gemm_xp_mfma(
    const ushort* __restrict__ Ah,
    const ushort* __restrict__ Bh, const ushort* __restrict__ Bl,
    float* __restrict__ P)
{
  constexpr int ASZ = 2 * 8 * 64 * 8;
  __shared__ ushort lds[3 * ASZ];
  const int tid = threadIdx.x;
  const int lane = tid & 63, wid = tid >> 6;
  const int wm = wid >> 1, wn = wid & 1;
  const int bm0 = blockIdx.y * 128;
  const size_t abase = (size_t)blockIdx.y * 16 * ASZ;
  const ushort* gsrc = (wid == 0) ? Ah : (wid == 1) ? Bh : Bl;
  const size_t gb = (wid == 0) ? abase : 0;
  f32x4 acc[4][2];
#pragma unroll
  for (int i = 0; i < 4; ++i) { acc[i][0] = (f32x4){0,0,0,0}; acc[i][1] = (f32x4){0,0,0,0}; }
  const int msel = wm * 4, nsel = wn * 2;
  const int kt0 = blockIdx.z * 8;
  for (int kt = kt0; kt < kt0 + 8; ++kt) {
    if (wid < 3) {
      const ushort* sbase = gsrc + gb + (size_t)kt * ASZ + lane * 8;
#pragma unroll
      for (int i = 0; i < 16; ++i)
        __builtin_amdgcn_global_load_lds(
            (const __attribute__((address_space(1))) void*)(sbase + i * 512),
            (__attribute__((address_space(3))) void*)(lds + wid * ASZ + i * 512),
            16, 0, 0);
    }
    __syncthreads();
#pragma unroll
    for (int kk = 0; kk < 2; ++kk) {
      short8v a_h[4], b_h[2], b_l[2];
#pragma unroll
      for (int i = 0; i < 4; ++i) {
        int ai = ((kk * 8 + msel + i) * 64 + lane) * 8;
        a_h[i] = *reinterpret_cast<const short8v*>(&lds[0 * ASZ + ai]);
      }
#pragma unroll
      for (int i = 0; i < 2; ++i) {
        int bi = ((kk * 8 + nsel + i) * 64 + lane) * 8;
        b_h[i] = *reinterpret_cast<const short8v*>(&lds[1 * ASZ + bi]);
        b_l[i] = *reinterpret_cast<const short8v*>(&lds[2 * ASZ + bi]);
      }
#pragma unroll
      for (int ms = 0; ms < 4; ++ms)
#pragma unroll
        for (int ns = 0; ns < 2; ++ns) {
          acc[ms][ns] = __builtin_amdgcn_mfma_f32_16x16x32_bf16(a_h[ms], b_h[ns], acc[ms][ns], 0, 0, 0);
          acc[ms][ns] = __builtin_amdgcn_mfma_f32_16x16x32_bf16(a_h[ms], b_l[ns], acc[ms][ns], 0, 0, 0);
        }
    }
    __syncthreads();
  }
  float* Pz = P + (size_t)blockIdx.z * BLQ * 64;
  const int cr = lane >> 4, cc = lane & 15;
#pragma unroll
  for (int ms = 0; ms < 4; ++ms) {
    int row0 = bm0 + (msel + ms) * 16 + cr * 4;
#pragma unroll
    for (int ns = 0; ns < 2; ++ns) {
      int col = (nsel + ns) * 16 + cc;
#pragma unroll
      for (int r = 0; r < 4; ++r)
        Pz[(size_t)(row0 + r) * 64 + col] = acc[ms][ns][r];
    }
  }
}

// ---------------- conv(dc=3)+silu from bf16 xz; emits fp32 XC + bf16 frag ----
__global__ __launch_bounds__(256) void conv_silu_kernel(
    const ushort* __restrict__ XZb, const float* __restrict__ cw,
    const float* __restrict__ cb, float* __restrict__ XC,
    ushort* __restrict__ XCf)
{
  int idx = blockIdx.x * 256 + threadIdx.x;   // unit of 8 d
  int d8 = idx & 127;                         // DI/8
  int bl = idx >> 7;
  int l = bl & (Lseq - 1);
  size_t base = (size_t)bl * (2 * DI) + d8 * 8;
  ushort8v cur = *reinterpret_cast<const ushort8v*>(&XZb[base]);
  ushort8v p1v = {}, p2v = {};
  if (l >= 1) p1v = *reinterpret_cast<const ushort8v*>(&XZb[base - 2 * DI]);
  if (l >= 2) p2v = *reinterpret_cast<const ushort8v*>(&XZb[base - 4 * DI]);
  float wv[24], bv[8];
#pragma unroll
  for (int q = 0; q < 6; ++q)
    *reinterpret_cast<float4*>(&wv[q * 4]) =
        *reinterpret_cast<const float4*>(&cw[d8 * 24 + q * 4]);
  *reinterpret_cast<float4*>(&bv[0]) = *reinterpret_cast<const float4*>(&cb[d8 * 8]);
  *reinterpret_cast<float4*>(&bv[4]) = *reinterpret_cast<const float4*>(&cb[d8 * 8 + 4]);
  float os[8];
  ushort hv[8];
#pragma unroll
  for (int e = 0; e < 8; ++e) {
    float acc = bv[e];
    acc = fmaf(bf2f(p2v[e]), wv[e * 3 + 0], acc);
    acc = fmaf(bf2f(p1v[e]), wv[e * 3 + 1], acc);
    acc = fmaf(bf2f(cur[e]), wv[e * 3 + 2], acc);
    float s = acc / (1.f + __expf(-acc));
    os[e] = s;
    hv[e] = bf16_rne(s);
  }
  float* op = &XC[(size_t)bl * DI + d8 * 8];
  *reinterpret_cast<float4*>(op) = *reinterpret_cast<float4*>(&os[0]);
  *reinterpret_cast<float4*>(op + 4) = *reinterpret_cast<float4*>(&os[4]);
  *reinterpret_cast<ushort8v*>(&XCf[frag_off(bl, d8 * 8, 16)]) =
      *reinterpret_cast<ushort8v*>(hv);
}

// ---------------- xpost: reduce 2 split-K slices + dt-proj + softplus --------
// grid (32, 17): y<16 -> dt part (dg=y, bm0=x*128); y==16 -> B/C compact reduce
__global__ __launch_bounds__(256) void xpost_kernel(
    const float* __restrict__ P, const float* __restrict__ dtw,
    const float* __restrict__ dtb, float* __restrict__ DTb,
    float* __restrict__ BCc)
{
  const int tid = threadIdx.x;
  const size_t SL = (size_t)BLQ * 64;
  if (blockIdx.y == 16) {
    int i0 = blockIdx.x * 4096 + tid;   // 32 blocks x 4096 = BLQ*32
#pragma unroll
    for (int i = 0; i < 16; ++i) {
      int idx = i0 + i * 256;
      int bt = idx >> 5, n = idx & 31;
      size_t g = (size_t)bt * 64 + 32 + n;
      BCc[idx] = P[g] + P[SL + g];
    }
    return;
  }
  const int dg = blockIdx.y, bm0 = blockIdx.x * 128;
  __shared__ float db[128][33];
  __shared__ float wt[64][33];
#pragma unroll
  for (int i = 0; i < 16; ++i) {
    int e = tid + i * 256;
    int r = e >> 5, c = e & 31;
    size_t g = (size_t)(bm0 + r) * 64 + c;
    db[r][c] = P[g] + P[SL + g];
  }
#pragma unroll
  for (int i = 0; i < 8; ++i) {
    int e = tid + i * 256;
    int r = e >> 5, c = e & 31;
    wt[r][c] = dtw[(size_t)(dg * 64 + r) * 32 + c];
  }
  __syncthreads();
  const int d_loc = tid & 63, wv = tid >> 6;
  const float bias = dtb[dg * 64 + d_loc];
#pragma unroll 4
  for (int i = 0; i < 32; ++i) {
    int r = wv + i * 4;
    float dot = 0.f;
#pragma unroll
    for (int c = 0; c < 32; ++c) dot = fmaf(db[r][c], wt[d_loc][c], dot);
    float v = dot + bias;
    DTb[(size_t)(bm0 + r) * DI + dg * 64 + d_loc] =
        (v > 15.f) ? v : log1pf(__expf(v));
  }
}

// ---------------- scan phase 1: chunk-end states + chunk dt-sums ------------
__global__ __launch_bounds__(256) void scan_p1_kernel(
    const float* __restrict__ DTb, const float* __restrict__ XC,
    const float* __restrict__ BCc, const float* __restrict__ Alog,
    float* __restrict__ HEND, float* __restrict__ DSUM)
{
  const int d = blockIdx.x * 256 + threadIdx.x;
  const int c = blockIdx.y, b = blockIdx.z;
  const int t0 = b * Lseq + c * CLEN;
  __shared__ float Bs[CLEN][16];
#pragma unroll
  for (int i = 0; i < 2; ++i) {
    int e = threadIdx.x + i * 256;
    Bs[e >> 4][e & 15] = BCc[(size_t)(t0 + (e >> 4)) * 32 + (e & 15)];
  }
  float An[16];
#pragma unroll
  for (int j = 0; j < 4; ++j) {
    float4 a = *reinterpret_cast<const float4*>(&Alog[d * 16 + j * 4]);
    An[j * 4 + 0] = -__expf(a.x); An[j * 4 + 1] = -__expf(a.y);
    An[j * 4 + 2] = -__expf(a.z); An[j * 4 + 3] = -__expf(a.w);
  }
  __syncthreads();
  float h[16] = {};
  float S = 0.f;
  for (int t = 0; t < CLEN; ++t) {
    size_t g = (size_t)(t0 + t) * DI + d;
    float dt = DTb[g], xc = XC[g];
    S += dt;
    float dtxc = dt * xc;
#pragma unroll
    for (int n = 0; n < 16; ++n)
      h[n] = fmaf(__expf(An[n] * dt), h[n], dtxc * Bs[t][n]);
  }
  size_t hb = ((size_t)(b * NCH + c) * DI + d) * 16;
#pragma unroll
  for (int j = 0; j < 4; ++j)
    *reinterpret_cast<float4*>(&HEND[hb + j * 4]) =
        *reinterpret_cast<float4*>(&h[j * 4]);
  DSUM[(size_t)(b * NCH + c) * DI + d] = S;
}

// ---------------- scan phase 2: serial chunk combine ----------------
__global__ __launch_bounds__(256) void scan_p2_kernel(
    float* __restrict__ HEND, const float* __restrict__ DSUM,
    const float* __restrict__ Alog)
{
  int id = blockIdx.x * 256 + threadIdx.x;   // (b,d,n)
  int n = id & 15, d = (id >> 4) & (DI - 1), b = id >> 14;
  float An = -__expf(Alog[d * 16 + n]);
  float hg = 0.f;
  for (int c = 0; c < NCH; ++c) {
    size_t hi = ((size_t)(b * NCH + c) * DI + d) * 16 + n;
    float hl = HEND[hi];
    float Dc = DSUM[(size_t)(b * NCH + c) * DI + d];
    HEND[hi] = hg;
    hg = fmaf(__expf(An * Dc), hg, hl);
  }
}

// ---------------- scan phase 3: exact recompute + epilogue + A-frag out -----
__global__ __launch_bounds__(256) void scan_p3_kernel(
    const float* __restrict__ XC, const float* __restrict__ DTb,
    const float* __restrict__ BCc, const ushort* __restrict__ XZb,
    const float* __restrict__ HEND, const float* __restrict__ Alog,
    const float* __restrict__ Dp, ushort* __restrict__ Af)
{
  const int tid = threadIdx.x;
  const int dg = blockIdx.x, c = blockIdx.y, b = blockIdx.z;
  const int d = dg * 256 + tid;
  const int t0 = b * Lseq + c * CLEN;
  __shared__ float BC[CLEN][32];
  __shared__ float ys[CLEN][264];
#pragma unroll
  for (int i = 0; i < 4; ++i) {
    int e = tid + i * 256;
    BC[e >> 5][e & 31] = BCc[(size_t)(t0 + (e >> 5)) * 32 + (e & 31)];
  }
  float An[16], h[16];
  size_t hb = ((size_t)(b * NCH + c) * DI + d) * 16;
#pragma unroll
  for (int j = 0; j < 4; ++j) {
    float4 a = *reinterpret_cast<const float4*>(&Alog[d * 16 + j * 4]);
    An[j * 4 + 0] = -__expf(a.x); An[j * 4 + 1] = -__expf(a.y);
    An[j * 4 + 2] = -__expf(a.z); An[j * 4 + 3] = -__expf(a.w);
    *reinterpret_cast<float4*>(&h[j * 4]) =
        *reinterpret_cast<const float4*>(&HEND[hb + j * 4]);
  }
  float Dpv = Dp[d];
  __syncthreads();
  for (int t = 0; t < CLEN; ++t) {
    size_t g = (size_t)(t0 + t) * DI + d;
    float dt = DTb[g], xc = XC[g];
    float z = bf2f(XZb[(size_t)(t0 + t) * (2 * DI) + DI + d]);
    float dtxc = dt * xc;
    float y = 0.f;
#pragma unroll
    for (int n = 0; n < 16; ++n) {
      h[n] = fmaf(__expf(An[n] * dt), h[n], dtxc * BC[t][n]);
      y = fmaf(h[n], BC[t][16 + n], y);
    }
    float sil = z / (1.f + __expf(-z));
    ys[t][tid] = (y + xc * Dpv) * sil;
  }
  __syncthreads();
#pragma unroll
  for (int i = 0; i < 4; ++i) {
    int u = tid + i * 256;
    int tt = u >> 5, j8 = u & 31;
    int row = t0 + tt;
    int kg = dg * 256 + j8 * 8;
    ushort hv[8];
#pragma unroll
    for (int e = 0; e < 8; ++e) hv[e] = bf16_rne(ys[tt][j8 * 8 + e]);
    *reinterpret_cast<ushort8v*>(&Af[frag_off(row, kg, 16)]) =
        *reinterpret_cast<ushort8v*>(hv);
  }
}

// ---------------- rmsnorm + A-fragment emit (K=512) ----------------
__global__ __launch_bounds__(256) void rmsnorm_kernel(const float* __restrict__ X,
    const float* __restrict__ W, float* __restrict__ O, ushort* __restrict__ Af) {
  int row = blockIdx.x * 4 + (threadIdx.x >> 6);
  int lane = threadIdx.x & 63;
  int k = lane * 8;
  const float* xp = X + (size_t)row * Dmodel + k;
  float4 v0 = *reinterpret_cast<const float4*>(xp);
  float4 v1 = *reinterpret_cast<const float4*>(xp + 4);
  float vs[8] = {v0.x, v0.y, v0.z, v0.w, v1.x, v1.y, v1.z, v1.w};
  float ss = 0.f;
#pragma unroll
  for (int e = 0; e < 8; ++e) ss = fmaf(vs[e], vs[e], ss);
#pragma unroll
  for (int o = 32; o >= 1; o >>= 1) ss += __shfl_xor(ss, o);
  float sc = rsqrtf(ss * (1.f / Dmodel) + 1e-5f);
  const float* wp = W + k;
  float4 w0 = *reinterpret_cast<const float4*>(wp);
  float4 w1 = *reinterpret_cast<const float4*>(wp + 4);
  float wsv[8] = {w0.x, w0.y, w0.z, w0.w, w1.x, w1.y, w1.z, w1.w};
  float os[8];
  ushort hv[8];
#pragma unroll
  for (int e = 0; e < 8; ++e) {
    os[e] = vs[e] * sc * wsv[e];
    hv[e] = bf16_rne(os[e]);
  }
  float* op = O + (size_t)row * Dmodel + k;
  *reinterpret_cast<float4*>(op) = *reinterpret_cast<float4*>(&os[0]);
  *reinterpret_cast<float4*>(op + 4) = *reinterpret_cast<float4*>(&os[4]);
  *reinterpret_cast<ushort8v*>(&Af[frag_off(row, k, 8)]) =
      *reinterpret_cast<ushort8v*>(hv);
}

// ---------------- mean-pool partials ----------------
__global__ __launch_bounds__(256) void pool_part_kernel(const float* __restrict__ H,
    float* __restrict__ part) {
  int b = blockIdx.x, dg = blockIdx.y, tc = blockIdx.z;
  int tid = threadIdx.x;
  int d = dg * 128 + (tid & 127);
  int ph = tid >> 7;
  const float* base = H + ((size_t)(b * Lseq + tc * 128 + ph * 64)) * Dmodel + d;
  float s = 0.f;
#pragma unroll 8
  for (int t = 0; t < 64; ++t) s += base[(size_t)t * Dmodel];
  __shared__ float red[256];
  red[tid] = s; __syncthreads();
  if (ph == 0)
    part[(size_t)(b * 8 + tc) * Dmodel + d] = red[tid] + red[tid + 128];
}

// ---------------- pool-final + tanh + fc head, one block per (b,j) ----------
__global__ __launch_bounds__(256) void pool_head_kernel(
    const float* __restrict__ part, const float* __restrict__ fcw,
    const float* __restrict__ fcb, float* __restrict__ out) {
  int b = blockIdx.x >> 1, j = blockIdx.x & 1;
  int tid = threadIdx.x;
  float s = 0.f;
  for (int d = tid; d < Dmodel; d += 256) {
    float p = 0.f;
#pragma unroll
    for (int tc = 0; tc < 8; ++tc) p += part[(size_t)(b * 8 + tc) * Dmodel + d];
    s += tanhf(p * (1.f / Lseq)) * fcw[j * Dmodel + d];
  }
#pragma unroll
  for (int o = 32; o >= 1; o >>= 1) s += __shfl_xor(s, o);
  __shared__ float w[4];
  if ((tid & 63) == 0) w[tid >> 6] = s;
  __syncthreads();
  if (tid == 0) out[b * 2 + j] = w[0] + w[1] + w[2] + w[3] + fcb[j];
}

extern "C" void kernel_launch(void* const* d_in, const int* in_sizes, int n_in,
                              void* d_out, int out_size, void* d_ws, size_t ws_size,
                              hipStream_t stream) {
  const int*   x      = (const int*)d_in[0];
  const float* emb    = (const float*)d_in[1];
  const float* norm_w = (const float*)d_in[2];
  const float* in_w   = (const float*)d_in[3];
  const float* conv_w = (const float*)d_in[4];
  const float* conv_b = (const float*)d_in[5];
  const float* xp_w   = (const float*)d_in[6];
  const float* dtp_w  = (const float*)d_in[7];
  const float* dtp_b  = (const float*)d_in[8];
  const float* A_log  = (const float*)d_in[9];
  const float* Dp     = (const float*)d_in[10];
  const float* out_w  = (const float*)d_in[11];
  const float* fc_w   = (const float*)d_in[12];
  const float* fc_b   = (const float*)d_in[13];
  float* out = (float*)d_out;

  // ---- disjoint workspace layout (ws_size ~256 MiB, usage ~108 MB) ----
  char* p = (char*)d_ws;
  auto alloc = [&](size_t bytes) { char* r = p; p += (bytes + 255) & ~255ull; return r; };
  ushort* XZb  = (ushort*)alloc((size_t)BLQ * 2 * DI * 2);      // 16 MB
  float*  XC   = (float*) alloc((size_t)BLQ * DI * 4);          // 16 MB
  ushort* XCf  = (ushort*)alloc((size_t)BLQ * DI * 2);          //  8 MB
  float*  DTb  = (float*) alloc((size_t)BLQ * DI * 4);          // 16 MB
  float*  BCc  = (float*) alloc((size_t)BLQ * 32 * 4);          // 0.5 MB
  float*  DBCP = (float*) alloc((size_t)2 * BLQ * 64 * 4);      //  2 MB
  float*  HEND = (float*) alloc((size_t)Bsz * NCH * DI * 16 * 4); // 8 MB
  float*  DSUM = (float*) alloc((size_t)Bsz * NCH * DI * 4);    // 0.5 MB
  float*  H    = (float*) alloc((size_t)BLQ * Dmodel * 4);      //  8 MB
  float*  H2   = (float*) alloc((size_t)BLQ * Dmodel * 4);      //  8 MB
  float*  PPART= (float*) alloc((size_t)Bsz * 8 * Dmodel * 4);
  ushort* AhI  = (ushort*)alloc((size_t)BLQ * Dmodel * 2);      //  4 MB
  ushort* AhO  = (ushort*)alloc((size_t)BLQ * DI * 2);          //  8 MB
  ushort* WIh  = (ushort*)alloc((size_t)2 * 2048 * 512 * 2);    //  4 MB
  ushort* WIl  = (ushort*)alloc((size_t)2 * 2048 * 512 * 2);    //  4 MB
  ushort* XPh  = (ushort*)alloc((size_t)2 * 131072 * 2);        // 0.5 MB
  ushort* XPl  = (ushort*)alloc((size_t)2 * 131072 * 2);
  ushort* WOh  = (ushort*)alloc((size_t)2 * 512 * 1024 * 2);    //  2 MB
  ushort* WOl  = (ushort*)alloc((size_t)2 * 512 * 1024 * 2);

  embed_kernel<<<BLQ * Dmodel / 8 / 256, 256, 0, stream>>>(x, emb, AhI);
  cvtw_kernel<<<1600, 256, 0, stream>>>(in_w, xp_w, out_w,
                                        WIh, WIl, XPh, XPl, WOh, WOl);

  for (int l = 0; l < NLAYERS; ++l) {
    const float* cw  = conv_w + (size_t)l * DI * 3;
    const float* cb  = conv_b + (size_t)l * DI;
    const float* dtw = dtp_w + (size_t)l * DI * RNK;
    const float* dtb = dtp_b + (size_t)l * DI;
    const float* Al  = A_log + (size_t)l * DI * NST;
    const float* dpl = Dp    + (size_t)l * DI;
    const float* nw  = norm_w + (size_t)l * Dmodel;
    const ushort* wih = WIh + (size_t)l * 2048 * 512;
    const ushort* wil = WIl + (size_t)l * 2048 * 512;
    const ushort* xph = XPh + (size_t)l * 131072;
    const ushort* xpl = XPl + (size_t)l * 131072;
    const ushort* woh = WOh + (size_t)l * 512 * 1024;
    const ushort* wol = WOl + (size_t)l * 512 * 1024;

    // xz = h @ in_w^T : M=4096, N=2048, K=512 -> bf16
    gemm_mfma<1><<<dim3(16, 32), 256, 0, stream>>>(AhI, wih, wil, XZb, 2 * DI, Dmodel);

    // xc = silu(conv(xi)) -> fp32 + bf16 fragments
    conv_silu_kernel<<<BLQ * DI / 8 / 256, 256, 0, stream>>>(XZb, cw, cb, XC, XCf);

    // dbc = xc @ xp_w^T : MFMA, split-K z=2
    gemm_xp_mfma<<<dim3(1, 32, 2), 256, 0, stream>>>(XCf, xph, xpl, DBCP);

    // reduce slices + dt = softplus(dbc[:,:32] @ dtw^T + dtb); compact B/C
    xpost_kernel<<<dim3(32, 17), 256, 0, stream>>>(DBCP, dtw, dtb, DTb, BCc);

    // chunked selective scan
    scan_p1_kernel<<<dim3(DI / 256, NCH, Bsz), 256, 0, stream>>>(
        DTb, XC, BCc, Al, HEND, DSUM);
    scan_p2_kernel<<<Bsz * DI * NST / 256, 256, 0, stream>>>(HEND, DSUM, Al);
    scan_p3_kernel<<<dim3(DI / 256, NCH, Bsz), 256, 0, stream>>>(
        XC, DTb, BCc, XZb, HEND, Al, dpl, AhO);

    // h2 = y @ out_w^T : M=4096, N=512, K=1024 -> fp32
    gemm_mfma<0><<<dim3(4, 32), 256, 0, stream>>>(AhO, woh, wol, H2, Dmodel, DI);

    // h = rmsnorm(h2) -> fp32 H + next layer's A fragments
    rmsnorm_kernel<<<BLQ / 4, 256, 0, stream>>>(H2, nw, H, AhI);
  }

  pool_part_kernel<<<dim3(Bsz, Dmodel / 128, 8), 256, 0, stream>>>(H, PPART);
  pool_head_kernel<<<2 * Bsz, 256, 0, stream>>>(PPART, fc_w, fc_b, out);
}